// Round 1
// baseline (987.575 us; speedup 1.0000x reference)
//
#include <hip/hip_runtime.h>
#include <hip/hip_bf16.h>
#include <math.h>

#define B_  4
#define S_  2048
#define DM  2048
#define H_  16
#define HD_ 128

typedef __bf16 bf16;
typedef __bf16 bf16x4 __attribute__((ext_vector_type(4)));
typedef __bf16 bf16x8 __attribute__((ext_vector_type(8)));
typedef float  f32x4  __attribute__((ext_vector_type(4)));

__device__ __forceinline__ void gload_lds16(const bf16* g, bf16* l) {
  __builtin_amdgcn_global_load_lds(
      (const __attribute__((address_space(1))) void*)g,
      (__attribute__((address_space(3))) void*)l, 16, 0, 0);
}

// ---------------- cast fp32 -> bf16 (vectorized) ----------------
__global__ void cast_f32_bf16(const float* __restrict__ src, bf16* __restrict__ dst, int n4) {
  int stride = gridDim.x * blockDim.x;
  for (int i = blockIdx.x * blockDim.x + threadIdx.x; i < n4; i += stride) {
    float4 v = reinterpret_cast<const float4*>(src)[i];
    bf16x4 o = { (bf16)v.x, (bf16)v.y, (bf16)v.z, (bf16)v.w };
    reinterpret_cast<bf16x4*>(dst)[i] = o;
  }
}

// ---------------- RoPE cos/sin table: tab[s][i] = {cos, sin} ----------------
__global__ void rope_table_k(float* __restrict__ tab) {
  int idx = blockIdx.x * blockDim.x + threadIdx.x;
  if (idx >= S_ * (HD_ / 2)) return;
  int pos = idx >> 6, i = idx & 63;
  float inv = powf(10000.0f, -(2.0f * i) / (float)HD_);
  float ang = (float)pos * inv;
  tab[2 * idx]     = cosf(ang);
  tab[2 * idx + 1] = sinf(ang);
}

// ---------------- RoPE in-place on bf16 [B,S,H,HD] (pairs 2i,2i+1) ----------------
__global__ void rope_apply_k(bf16* __restrict__ t, const float* __restrict__ tab, float scale) {
  const int NP = B_ * S_ * H_ * (HD_ / 2);
  int stride = gridDim.x * blockDim.x;
  for (int idx = blockIdx.x * blockDim.x + threadIdx.x; idx < NP; idx += stride) {
    int i = idx & 63;
    int h = (idx >> 6) & (H_ - 1);
    int s = (idx >> 10) & (S_ - 1);
    int b = idx >> 21;
    size_t base = ((size_t)(b * S_ + s)) * DM + h * HD_ + 2 * i;
    float2 cs = reinterpret_cast<const float2*>(tab)[s * 64 + i];
    float x0 = (float)t[base], x1 = (float)t[base + 1];
    t[base]     = (bf16)((x0 * cs.x - x1 * cs.y) * scale);
    t[base + 1] = (bf16)((x0 * cs.y + x1 * cs.x) * scale);
  }
}

// ---------------- bf16 GEMM: C[M,N] = A[M,K] * Bt[N,K]^T ----------------
// m97 structure: 128x128 tile, 4 waves (2x2 of 64x64), BK=32, global_load_lds w16.
// OUTF=0: bf16 out; OUTF=1: f32 out + bias.
template<int OUTF>
__global__ __launch_bounds__(256, 2)
void gemm_bt(const bf16* __restrict__ A, const bf16* __restrict__ Bt,
             bf16* __restrict__ Cb, float* __restrict__ Cf,
             const float* __restrict__ bias, int M, int N, int K) {
  __shared__ bf16 As[128][32];
  __shared__ bf16 Bs[128][32];
  const int tid = threadIdx.x;
  const int w = tid >> 6, l = tid & 63;
  const int row0 = blockIdx.x * 128, col0 = blockIdx.y * 128;
  const int wm = (w >> 1) * 64, wn = (w & 1) * 64;
  const int lr = l & 15, lg = l >> 4;
  f32x4 acc[4][4] = {};
  for (int kt = 0; kt < K; kt += 32) {
    __syncthreads();
#pragma unroll
    for (int i = 0; i < 2; ++i) {
      int eo = (i * 4096 + w * 1024) / 2 + l * 8;  // element offset incl. lane
      int r = eo >> 5, c = eo & 31;
      gload_lds16(A  + (size_t)(row0 + r) * K + kt + c, &As[0][0] + i * 2048 + w * 512);
      gload_lds16(Bt + (size_t)(col0 + r) * K + kt + c, &Bs[0][0] + i * 2048 + w * 512);
    }
    asm volatile("s_waitcnt vmcnt(0)" ::: "memory");
    __syncthreads();
    bf16x8 af[4], bfr[4];
#pragma unroll
    for (int mi = 0; mi < 4; ++mi)
      af[mi] = *reinterpret_cast<const bf16x8*>(&As[wm + mi * 16 + lr][lg * 8]);
#pragma unroll
    for (int ni = 0; ni < 4; ++ni)
      bfr[ni] = *reinterpret_cast<const bf16x8*>(&Bs[wn + ni * 16 + lr][lg * 8]);
#pragma unroll
    for (int mi = 0; mi < 4; ++mi)
#pragma unroll
      for (int ni = 0; ni < 4; ++ni)
        acc[mi][ni] = __builtin_amdgcn_mfma_f32_16x16x32_bf16(af[mi], bfr[ni], acc[mi][ni], 0, 0, 0);
  }
#pragma unroll
  for (int mi = 0; mi < 4; ++mi) {
    int rb = row0 + wm + mi * 16 + lg * 4;
#pragma unroll
    for (int ni = 0; ni < 4; ++ni) {
      int cc = col0 + wn + ni * 16 + lr;
#pragma unroll
      for (int j = 0; j < 4; ++j) {
        size_t off = (size_t)(rb + j) * N + cc;
        if (OUTF) Cf[off] = acc[mi][ni][j] + bias[cc];
        else      Cb[off] = (bf16)acc[mi][ni][j];
      }
    }
  }
}

// ---------------- causal flash attention ----------------
// block = (qt, h, b), 4 waves x 16 q-rows = 64 q-rows; KBLK=64.
// Q pre-scaled by 1/sqrt(HD). Output ctx bf16 at [b,s,h,d].
__global__ __launch_bounds__(256, 2)
void attn_fwd(const bf16* __restrict__ Q, const bf16* __restrict__ K,
              const bf16* __restrict__ V, bf16* __restrict__ O) {
  __shared__ bf16 Ks[64][128];
  __shared__ bf16 Vt[128][64];
  __shared__ bf16 Ps[4][16][64];
  const int tid = threadIdx.x;
  const int w = tid >> 6, l = tid & 63;
  const int qt = blockIdx.x, h = blockIdx.y, b = blockIdx.z;
  const int lr = l & 15, lg = l >> 4;
  const size_t bbase = (size_t)b * S_ * DM + (size_t)h * HD_;
  const int q0 = qt * 64 + w * 16;

  bf16x8 qf[4];
#pragma unroll
  for (int kb = 0; kb < 4; ++kb)
    qf[kb] = *reinterpret_cast<const bf16x8*>(Q + bbase + (size_t)(q0 + lr) * DM + kb * 32 + lg * 8);

  float mrow[4] = {-INFINITY, -INFINITY, -INFINITY, -INFINITY};
  float lrow[4] = {0.f, 0.f, 0.f, 0.f};
  f32x4 o[8] = {};

  for (int kt = 0; kt <= qt; ++kt) {
    __syncthreads();
    // stage K tile [64][128] via global_load_lds
#pragma unroll
    for (int i = 0; i < 4; ++i) {
      int eo = (i * 4096 + w * 1024) / 2 + l * 8;
      int r = eo >> 7, c = eo & 127;
      gload_lds16(K + bbase + (size_t)(kt * 64 + r) * DM + c, &Ks[0][0] + i * 2048 + w * 512);
    }
    // stage V transposed: Vt[d][kv]
    {
      int r = tid >> 2, c0 = (tid & 3) * 32;
#pragma unroll
      for (int u = 0; u < 4; ++u) {
        bf16x8 v = *reinterpret_cast<const bf16x8*>(V + bbase + (size_t)(kt * 64 + r) * DM + c0 + u * 8);
#pragma unroll
        for (int j = 0; j < 8; ++j) Vt[c0 + u * 8 + j][r] = v[j];
      }
    }
    asm volatile("s_waitcnt vmcnt(0)" ::: "memory");
    __syncthreads();

    // QK^T : S-tile 16x64 per wave
    f32x4 sc[4];
#pragma unroll
    for (int cb = 0; cb < 4; ++cb) {
      sc[cb] = f32x4{0.f, 0.f, 0.f, 0.f};
#pragma unroll
      for (int kb = 0; kb < 4; ++kb) {
        bf16x8 kf = *reinterpret_cast<const bf16x8*>(&Ks[cb * 16 + lr][kb * 32 + lg * 8]);
        sc[cb] = __builtin_amdgcn_mfma_f32_16x16x32_bf16(qf[kb], kf, sc[cb], 0, 0, 0);
      }
    }
    // causal mask
#pragma unroll
    for (int cb = 0; cb < 4; ++cb) {
      int kk = kt * 64 + cb * 16 + lr;
#pragma unroll
      for (int j = 0; j < 4; ++j) {
        int qq = q0 + lg * 4 + j;
        if (kk > qq) sc[cb][j] = -INFINITY;
      }
    }
    // online softmax (row state replicated across the 16-lane group)
    float scalef[4], sum[4];
#pragma unroll
    for (int j = 0; j < 4; ++j) {
      float v = fmaxf(fmaxf(sc[0][j], sc[1][j]), fmaxf(sc[2][j], sc[3][j]));
      v = fmaxf(v, __shfl_xor(v, 1));
      v = fmaxf(v, __shfl_xor(v, 2));
      v = fmaxf(v, __shfl_xor(v, 4));
      v = fmaxf(v, __shfl_xor(v, 8));
      float mnew = fmaxf(mrow[j], v);
      scalef[j] = __expf(mrow[j] - mnew);
      mrow[j] = mnew;
      sum[j] = 0.f;
    }
#pragma unroll
    for (int cb = 0; cb < 4; ++cb)
#pragma unroll
      for (int j = 0; j < 4; ++j) {
        float p = __expf(sc[cb][j] - mrow[j]);
        sc[cb][j] = p;
        sum[j] += p;
      }
#pragma unroll
    for (int j = 0; j < 4; ++j) {
      float v = sum[j];
      v += __shfl_xor(v, 1);
      v += __shfl_xor(v, 2);
      v += __shfl_xor(v, 4);
      v += __shfl_xor(v, 8);
      lrow[j] = lrow[j] * scalef[j] + v;
    }
#pragma unroll
    for (int nb = 0; nb < 8; ++nb)
#pragma unroll
      for (int j = 0; j < 4; ++j) o[nb][j] *= scalef[j];
    // P -> LDS (per-wave private region)
#pragma unroll
    for (int cb = 0; cb < 4; ++cb)
#pragma unroll
      for (int j = 0; j < 4; ++j)
        Ps[w][lg * 4 + j][cb * 16 + lr] = (bf16)sc[cb][j];
    // PV
    bf16x8 pf[2];
#pragma unroll
    for (int kc = 0; kc < 2; ++kc)
      pf[kc] = *reinterpret_cast<const bf16x8*>(&Ps[w][lr][kc * 32 + lg * 8]);
#pragma unroll
    for (int nb = 0; nb < 8; ++nb)
#pragma unroll
      for (int kc = 0; kc < 2; ++kc) {
        bf16x8 vf = *reinterpret_cast<const bf16x8*>(&Vt[nb * 16 + lr][kc * 32 + lg * 8]);
        o[nb] = __builtin_amdgcn_mfma_f32_16x16x32_bf16(pf[kc], vf, o[nb], 0, 0, 0);
      }
  }
  // epilogue: normalize and store ctx (bf16) at [b, q, h*HD + d]
#pragma unroll
  for (int j = 0; j < 4; ++j) {
    float inv = 1.0f / lrow[j];
    int qq = q0 + lg * 4 + j;
    size_t rowoff = bbase + (size_t)qq * DM;
#pragma unroll
    for (int nb = 0; nb < 8; ++nb)
      O[rowoff + nb * 16 + lr] = (bf16)(o[nb][j] * inv);
  }
}

extern "C" void kernel_launch(void* const* d_in, const int* in_sizes, int n_in,
                              void* d_out, int out_size, void* d_ws, size_t ws_size,
                              hipStream_t stream) {
  const float* x  = (const float*)d_in[0];
  const float* Wq = (const float*)d_in[1];
  const float* Wk = (const float*)d_in[2];
  const float* Wv = (const float*)d_in[3];
  const float* Wo = (const float*)d_in[4];
  const float* bo = (const float*)d_in[5];
  float* out = (float*)d_out;

  const size_t NX = (size_t)B_ * S_ * DM;  // 16,777,216
  const size_t NW = (size_t)DM * DM;       //  4,194,304
  char* ws = (char*)d_ws;
  bf16* xb   = (bf16*)ws; ws += NX * 2;
  bf16* wqb  = (bf16*)ws; ws += NW * 2;
  bf16* wkb  = (bf16*)ws; ws += NW * 2;
  bf16* wvb  = (bf16*)ws; ws += NW * 2;
  bf16* wob  = (bf16*)ws; ws += NW * 2;
  bf16* qb   = (bf16*)ws; ws += NX * 2;
  bf16* kb   = (bf16*)ws; ws += NX * 2;
  bf16* vb   = (bf16*)ws; ws += NX * 2;
  bf16* ctxb = (bf16*)ws; ws += NX * 2;
  float* tab = (float*)ws; ws += (size_t)S_ * 64 * 2 * sizeof(float);

  cast_f32_bf16<<<(int)((NX / 4 + 255) / 256), 256, 0, stream>>>(x, xb, (int)(NX / 4));
  cast_f32_bf16<<<(int)((NW / 4 + 255) / 256), 256, 0, stream>>>(Wq, wqb, (int)(NW / 4));
  cast_f32_bf16<<<(int)((NW / 4 + 255) / 256), 256, 0, stream>>>(Wk, wkb, (int)(NW / 4));
  cast_f32_bf16<<<(int)((NW / 4 + 255) / 256), 256, 0, stream>>>(Wv, wvb, (int)(NW / 4));
  cast_f32_bf16<<<(int)((NW / 4 + 255) / 256), 256, 0, stream>>>(Wo, wob, (int)(NW / 4));
  rope_table_k<<<(S_ * 64 + 255) / 256, 256, 0, stream>>>(tab);

  const int M = B_ * S_;
  dim3 gg(M / 128, DM / 128);
  gemm_bt<0><<<gg, 256, 0, stream>>>(xb, wqb, qb, nullptr, nullptr, M, DM, DM);
  gemm_bt<0><<<gg, 256, 0, stream>>>(xb, wkb, kb, nullptr, nullptr, M, DM, DM);
  gemm_bt<0><<<gg, 256, 0, stream>>>(xb, wvb, vb, nullptr, nullptr, M, DM, DM);

  const int NP = B_ * S_ * H_ * (HD_ / 2);
  rope_apply_k<<<(NP + 255) / 256, 256, 0, stream>>>(qb, tab, 0.08838834764831845f);
  rope_apply_k<<<(NP + 255) / 256, 256, 0, stream>>>(kb, tab, 1.0f);

  attn_fwd<<<dim3(S_ / 64, H_, B_), 256, 0, stream>>>(qb, kb, vb, ctxb);

  gemm_bt<1><<<gg, 256, 0, stream>>>(ctxb, wob, nullptr, out, bo, M, DM, DM);
}

// Round 3
// 650.995 us; speedup vs baseline: 1.5170x; 1.5170x over previous
//
#include <hip/hip_runtime.h>
#include <hip/hip_bf16.h>
#include <math.h>

#define B_  4
#define S_  2048
#define DM  2048
#define H_  16
#define HD_ 128

typedef __bf16 bf16;
typedef __bf16 bf16x4 __attribute__((ext_vector_type(4)));
typedef __bf16 bf16x8 __attribute__((ext_vector_type(8)));
typedef float  f32x4  __attribute__((ext_vector_type(4)));

__device__ __forceinline__ void gload_lds16(const bf16* g, bf16* l) {
  __builtin_amdgcn_global_load_lds(
      (const __attribute__((address_space(1))) void*)g,
      (__attribute__((address_space(3))) void*)l, 16, 0, 0);
}

// ---------------- cast fp32 -> bf16 (vectorized) ----------------
__global__ void cast_f32_bf16(const float* __restrict__ src, bf16* __restrict__ dst, int n4) {
  int stride = gridDim.x * blockDim.x;
  for (int i = blockIdx.x * blockDim.x + threadIdx.x; i < n4; i += stride) {
    float4 v = reinterpret_cast<const float4*>(src)[i];
    bf16x4 o = { (bf16)v.x, (bf16)v.y, (bf16)v.z, (bf16)v.w };
    reinterpret_cast<bf16x4*>(dst)[i] = o;
  }
}

// ---------------- RoPE cos/sin table: tab[s][i] = {cos, sin} ----------------
__global__ void rope_table_k(float* __restrict__ tab) {
  int idx = blockIdx.x * blockDim.x + threadIdx.x;
  if (idx >= S_ * (HD_ / 2)) return;
  int pos = idx >> 6, i = idx & 63;
  float inv = powf(10000.0f, -(2.0f * i) / (float)HD_);
  float ang = (float)pos * inv;
  tab[2 * idx]     = cosf(ang);
  tab[2 * idx + 1] = sinf(ang);
}

// ---------------- RoPE in-place on bf16 [B,S,H,HD] (pairs 2i,2i+1) ----------------
__global__ void rope_apply_k(bf16* __restrict__ t, const float* __restrict__ tab, float scale) {
  const int NP = B_ * S_ * H_ * (HD_ / 2);
  int stride = gridDim.x * blockDim.x;
  for (int idx = blockIdx.x * blockDim.x + threadIdx.x; idx < NP; idx += stride) {
    int i = idx & 63;
    int h = (idx >> 6) & (H_ - 1);
    int s = (idx >> 10) & (S_ - 1);
    int b = idx >> 21;
    size_t base = ((size_t)(b * S_ + s)) * DM + h * HD_ + 2 * i;
    float2 cs = reinterpret_cast<const float2*>(tab)[s * 64 + i];
    float x0 = (float)t[base], x1 = (float)t[base + 1];
    t[base]     = (bf16)((x0 * cs.x - x1 * cs.y) * scale);
    t[base + 1] = (bf16)((x0 * cs.y + x1 * cs.x) * scale);
  }
}

// ---------------- bf16 GEMM: C[M,N] = A[M,K] * Bt[N,K]^T ----------------
// OUTF=0: bf16 out row-major [M][N]
// OUTF=1: f32 out + bias
// OUTF=2: bf16 out transposed to vt[b][h][d][s]  (N==DM, M==B_*S_)
template<int OUTF>
__global__ __launch_bounds__(256, 2)
void gemm_bt(const bf16* __restrict__ A, const bf16* __restrict__ Bt,
             bf16* __restrict__ Cb, float* __restrict__ Cf,
             const float* __restrict__ bias, int M, int N, int K) {
  __shared__ bf16 As[128][32];
  __shared__ bf16 Bs[128][32];
  const int tid = threadIdx.x;
  const int w = tid >> 6, l = tid & 63;
  const int row0 = blockIdx.x * 128, col0 = blockIdx.y * 128;
  const int wm = (w >> 1) * 64, wn = (w & 1) * 64;
  const int lr = l & 15, lg = l >> 4;
  f32x4 acc[4][4] = {};
  for (int kt = 0; kt < K; kt += 32) {
    __syncthreads();
#pragma unroll
    for (int i = 0; i < 2; ++i) {
      int eo = (i * 4096 + w * 1024) / 2 + l * 8;  // element offset incl. lane
      int r = eo >> 5, c = eo & 31;
      gload_lds16(A  + (size_t)(row0 + r) * K + kt + c, &As[0][0] + i * 2048 + w * 512);
      gload_lds16(Bt + (size_t)(col0 + r) * K + kt + c, &Bs[0][0] + i * 2048 + w * 512);
    }
    asm volatile("s_waitcnt vmcnt(0)" ::: "memory");
    __syncthreads();
    bf16x8 af[4], bfr[4];
#pragma unroll
    for (int mi = 0; mi < 4; ++mi)
      af[mi] = *reinterpret_cast<const bf16x8*>(&As[wm + mi * 16 + lr][lg * 8]);
#pragma unroll
    for (int ni = 0; ni < 4; ++ni)
      bfr[ni] = *reinterpret_cast<const bf16x8*>(&Bs[wn + ni * 16 + lr][lg * 8]);
#pragma unroll
    for (int mi = 0; mi < 4; ++mi)
#pragma unroll
      for (int ni = 0; ni < 4; ++ni)
        acc[mi][ni] = __builtin_amdgcn_mfma_f32_16x16x32_bf16(af[mi], bfr[ni], acc[mi][ni], 0, 0, 0);
  }
#pragma unroll
  for (int mi = 0; mi < 4; ++mi) {
    int rb = row0 + wm + mi * 16 + lg * 4;
#pragma unroll
    for (int ni = 0; ni < 4; ++ni) {
      int cc = col0 + wn + ni * 16 + lr;
      if (OUTF == 2) {
        // transposed V write: vt[b][h][d][s], 4 s-contiguous per lane
        int bb = rb >> 11, s = rb & 2047;
        int hh = cc >> 7, dd = cc & 127;
        bf16x4 pack = { (bf16)acc[mi][ni][0], (bf16)acc[mi][ni][1],
                        (bf16)acc[mi][ni][2], (bf16)acc[mi][ni][3] };
        *reinterpret_cast<bf16x4*>(Cb + (((size_t)(bb * H_ + hh) * HD_ + dd) << 11) + s) = pack;
      } else {
#pragma unroll
        for (int j = 0; j < 4; ++j) {
          size_t off = (size_t)(rb + j) * N + cc;
          if (OUTF == 1) Cf[off] = acc[mi][ni][j] + bias[cc];
          else           Cb[off] = (bf16)acc[mi][ni][j];
        }
      }
    }
  }
}

// ---------------- causal flash attention ----------------
// block = 512 thr (8 waves), QBLK=128 (16 q-rows/wave), KVBLK=64.
// K staged [64][128] XOR-swizzled; V pre-transposed in global vt[b][h][d][s],
// staged [128][64] XOR-swizzled. Double-buffered, counted vmcnt(4).
// Q pre-scaled by 1/sqrt(HD). Output ctx bf16 at [b,s,h*HD+d].
__global__ __launch_bounds__(512, 4)
void attn_fwd(const bf16* __restrict__ Q, const bf16* __restrict__ K,
              const bf16* __restrict__ Vt, bf16* __restrict__ O) {
  __shared__ bf16 Ks[2][64 * 128];
  __shared__ bf16 Vs[2][128 * 64];
  __shared__ bf16 Ps[8][16 * 64];
  const int tid = threadIdx.x;
  const int w = tid >> 6, l = tid & 63;
  const int lr = l & 15, lg = l >> 4;
  const int qt = (int)(gridDim.x - 1 - blockIdx.x);  // big tiles launch first
  const int h = blockIdx.y, b = blockIdx.z;
  const size_t bbase = (size_t)b * S_ * DM + (size_t)h * HD_;
  const bf16* vtb = Vt + (size_t)(b * H_ + h) * HD_ * S_;
  const int q0 = qt * 128 + w * 16;
  const int ktmax = 2 * qt + 1;

  bf16x8 qf[4];
#pragma unroll
  for (int kb = 0; kb < 4; ++kb)
    qf[kb] = *reinterpret_cast<const bf16x8*>(Q + bbase + (size_t)(q0 + lr) * DM + kb * 32 + lg * 8);

  float mrow[4] = {-INFINITY, -INFINITY, -INFINITY, -INFINITY};
  float lrow[4] = {0.f, 0.f, 0.f, 0.f};
  f32x4 o[8] = {};

  // prologue: stage tile 0 into buf 0 (4 gloads per wave: 2 K + 2 V)
#pragma unroll
  for (int i = 0; i < 2; ++i) {
    int X = w * 2048 + i * 1024 + l * 16;
    int r = X >> 8, scb = (X & 255) ^ ((r & 7) << 4);
    gload_lds16(K + bbase + (size_t)r * DM + (scb >> 1), &Ks[0][(w * 2048 + i * 1024) >> 1]);
  }
#pragma unroll
  for (int i = 0; i < 2; ++i) {
    int X = w * 2048 + i * 1024 + l * 16;
    int d = X >> 7, scb = (X & 127) ^ ((d & 7) << 4);
    gload_lds16(vtb + (size_t)d * S_ + (scb >> 1), &Vs[0][(w * 2048 + i * 1024) >> 1]);
  }

  for (int kt = 0; kt <= ktmax; ++kt) {
    const int buf = kt & 1;
    if (kt < ktmax) {
      const int nk = (kt + 1) * 64;
#pragma unroll
      for (int i = 0; i < 2; ++i) {
        int X = w * 2048 + i * 1024 + l * 16;
        int r = X >> 8, scb = (X & 255) ^ ((r & 7) << 4);
        gload_lds16(K + bbase + (size_t)(nk + r) * DM + (scb >> 1),
                    &Ks[buf ^ 1][(w * 2048 + i * 1024) >> 1]);
      }
#pragma unroll
      for (int i = 0; i < 2; ++i) {
        int X = w * 2048 + i * 1024 + l * 16;
        int d = X >> 7, scb = (X & 127) ^ ((d & 7) << 4);
        gload_lds16(vtb + (size_t)d * S_ + nk + (scb >> 1),
                    &Vs[buf ^ 1][(w * 2048 + i * 1024) >> 1]);
      }
      asm volatile("s_waitcnt vmcnt(4)" ::: "memory");  // current tile done, next in flight
    } else {
      asm volatile("s_waitcnt vmcnt(0)" ::: "memory");
    }
    __builtin_amdgcn_s_barrier();

    // ---- QK^T : 16 q-rows x 64 kv per wave ----
    f32x4 sc4[4];
    __builtin_amdgcn_s_setprio(1);
#pragma unroll
    for (int cb = 0; cb < 4; ++cb) {
      sc4[cb] = f32x4{0.f, 0.f, 0.f, 0.f};
      int r = cb * 16 + lr;
#pragma unroll
      for (int kb = 0; kb < 4; ++kb) {
        int off = r * 256 + ((kb * 64 + lg * 16) ^ ((lr & 7) << 4));
        bf16x8 kf = *reinterpret_cast<const bf16x8*>((const char*)Ks[buf] + off);
        sc4[cb] = __builtin_amdgcn_mfma_f32_16x16x32_bf16(qf[kb], kf, sc4[cb], 0, 0, 0);
      }
    }
    __builtin_amdgcn_s_setprio(0);

    // ---- causal mask (only when tile straddles the diagonal for this wave) ----
    const int kv0 = kt * 64;
    if (kv0 + 63 > q0) {
#pragma unroll
      for (int cb = 0; cb < 4; ++cb) {
        int kk = kv0 + cb * 16 + lr;
#pragma unroll
        for (int j = 0; j < 4; ++j)
          if (kk > q0 + lg * 4 + j) sc4[cb][j] = -INFINITY;
      }
    }

    // ---- online softmax (row state replicated across 16-lane group) ----
    float scalef[4];
#pragma unroll
    for (int j = 0; j < 4; ++j) {
      float v = fmaxf(fmaxf(sc4[0][j], sc4[1][j]), fmaxf(sc4[2][j], sc4[3][j]));
      v = fmaxf(v, __shfl_xor(v, 1));
      v = fmaxf(v, __shfl_xor(v, 2));
      v = fmaxf(v, __shfl_xor(v, 4));
      v = fmaxf(v, __shfl_xor(v, 8));
      float mnew = fmaxf(mrow[j], v);
      scalef[j] = __expf(mrow[j] - mnew);
      mrow[j] = mnew;
    }
    float sum[4] = {0.f, 0.f, 0.f, 0.f};
#pragma unroll
    for (int cb = 0; cb < 4; ++cb)
#pragma unroll
      for (int j = 0; j < 4; ++j) {
        float p = __expf(sc4[cb][j] - mrow[j]);
        sc4[cb][j] = p;
        sum[j] += p;
      }
#pragma unroll
    for (int j = 0; j < 4; ++j) {
      float v = sum[j];
      v += __shfl_xor(v, 1);
      v += __shfl_xor(v, 2);
      v += __shfl_xor(v, 4);
      v += __shfl_xor(v, 8);
      lrow[j] = lrow[j] * scalef[j] + v;
    }
#pragma unroll
    for (int nb = 0; nb < 8; ++nb)
#pragma unroll
      for (int j = 0; j < 4; ++j) o[nb][j] *= scalef[j];

    // ---- P -> LDS (wave-private, swizzled) ----
#pragma unroll
    for (int cb = 0; cb < 4; ++cb)
#pragma unroll
      for (int j = 0; j < 4; ++j) {
        int rr = lg * 4 + j;
        int off = rr * 128 + ((cb * 32 + lr * 2) ^ ((rr & 7) << 4));
        *(bf16*)((char*)Ps[w] + off) = (bf16)sc4[cb][j];
      }

    // ---- PV ----
    bf16x8 pf[2];
#pragma unroll
    for (int kc = 0; kc < 2; ++kc) {
      int off = lr * 128 + ((kc * 64 + lg * 16) ^ ((lr & 7) << 4));
      pf[kc] = *reinterpret_cast<const bf16x8*>((const char*)Ps[w] + off);
    }
    __builtin_amdgcn_s_setprio(1);
#pragma unroll
    for (int nb = 0; nb < 8; ++nb) {
      int d = nb * 16 + lr;
#pragma unroll
      for (int kc = 0; kc < 2; ++kc) {
        int off = d * 128 + ((kc * 64 + lg * 16) ^ ((lr & 7) << 4));
        bf16x8 vf = *reinterpret_cast<const bf16x8*>((const char*)Vs[buf] + off);
        o[nb] = __builtin_amdgcn_mfma_f32_16x16x32_bf16(pf[kc], vf, o[nb], 0, 0, 0);
      }
    }
    __builtin_amdgcn_s_setprio(0);

    asm volatile("s_waitcnt lgkmcnt(0)" ::: "memory");  // all LDS reads of buf retired
    __builtin_amdgcn_s_barrier();                       // before buf is restaged
  }

  // ---- epilogue: normalize, store ctx bf16 at [b, q, h*HD+d] ----
#pragma unroll
  for (int j = 0; j < 4; ++j) {
    float inv = 1.0f / lrow[j];
    size_t rowoff = bbase + (size_t)(q0 + lg * 4 + j) * DM;
#pragma unroll
    for (int nb = 0; nb < 8; ++nb)
      O[rowoff + nb * 16 + lr] = (bf16)(o[nb][j] * inv);
  }
}

extern "C" void kernel_launch(void* const* d_in, const int* in_sizes, int n_in,
                              void* d_out, int out_size, void* d_ws, size_t ws_size,
                              hipStream_t stream) {
  const float* x  = (const float*)d_in[0];
  const float* Wq = (const float*)d_in[1];
  const float* Wk = (const float*)d_in[2];
  const float* Wv = (const float*)d_in[3];
  const float* Wo = (const float*)d_in[4];
  const float* bo = (const float*)d_in[5];
  float* out = (float*)d_out;

  const size_t NX = (size_t)B_ * S_ * DM;  // 16,777,216
  const size_t NW = (size_t)DM * DM;       //  4,194,304
  char* ws = (char*)d_ws;
  bf16* xb   = (bf16*)ws; ws += NX * 2;
  bf16* wqb  = (bf16*)ws; ws += NW * 2;
  bf16* wkb  = (bf16*)ws; ws += NW * 2;
  bf16* wvb  = (bf16*)ws; ws += NW * 2;
  bf16* wob  = (bf16*)ws; ws += NW * 2;
  bf16* qb   = (bf16*)ws; ws += NX * 2;
  bf16* kb   = (bf16*)ws; ws += NX * 2;
  bf16* vt   = (bf16*)ws; ws += NX * 2;   // V pre-transposed [B][H][HD][S]
  bf16* ctxb = (bf16*)ws; ws += NX * 2;
  float* tab = (float*)ws; ws += (size_t)S_ * 64 * 2 * sizeof(float);

  cast_f32_bf16<<<(int)((NX / 4 + 255) / 256), 256, 0, stream>>>(x, xb, (int)(NX / 4));
  cast_f32_bf16<<<(int)((NW / 4 + 255) / 256), 256, 0, stream>>>(Wq, wqb, (int)(NW / 4));
  cast_f32_bf16<<<(int)((NW / 4 + 255) / 256), 256, 0, stream>>>(Wk, wkb, (int)(NW / 4));
  cast_f32_bf16<<<(int)((NW / 4 + 255) / 256), 256, 0, stream>>>(Wv, wvb, (int)(NW / 4));
  cast_f32_bf16<<<(int)((NW / 4 + 255) / 256), 256, 0, stream>>>(Wo, wob, (int)(NW / 4));
  rope_table_k<<<(S_ * 64 + 255) / 256, 256, 0, stream>>>(tab);

  const int M = B_ * S_;
  dim3 gg(M / 128, DM / 128);
  gemm_bt<0><<<gg, 256, 0, stream>>>(xb, wqb, qb, nullptr, nullptr, M, DM, DM);
  gemm_bt<0><<<gg, 256, 0, stream>>>(xb, wkb, kb, nullptr, nullptr, M, DM, DM);
  gemm_bt<2><<<gg, 256, 0, stream>>>(xb, wvb, vt, nullptr, nullptr, M, DM, DM);

  const int NP = B_ * S_ * H_ * (HD_ / 2);
  rope_apply_k<<<(NP + 255) / 256, 256, 0, stream>>>(qb, tab, 0.08838834764831845f);
  rope_apply_k<<<(NP + 255) / 256, 256, 0, stream>>>(kb, tab, 1.0f);

  attn_fwd<<<dim3(S_ / 128, H_, B_), 512, 0, stream>>>(qb, kb, vt, ctxb);

  gemm_bt<1><<<gg, 256, 0, stream>>>(ctxb, wob, nullptr, out, bo, M, DM, DM);
}

// Round 4
// 487.052 us; speedup vs baseline: 2.0277x; 1.3366x over previous
//
#include <hip/hip_runtime.h>
#include <hip/hip_bf16.h>
#include <math.h>

#define B_  4
#define S_  2048
#define DM  2048
#define H_  16
#define HD_ 128

typedef __bf16 bf16;
typedef __bf16 bf16x4 __attribute__((ext_vector_type(4)));
typedef __bf16 bf16x8 __attribute__((ext_vector_type(8)));
typedef float  f32x4  __attribute__((ext_vector_type(4)));

__device__ __forceinline__ void gload_lds16(const bf16* g, bf16* l) {
  __builtin_amdgcn_global_load_lds(
      (const __attribute__((address_space(1))) void*)g,
      (__attribute__((address_space(3))) void*)l, 16, 0, 0);
}

// ---------------- cast fp32 -> bf16 (vectorized) ----------------
__global__ void cast_f32_bf16(const float* __restrict__ src, bf16* __restrict__ dst, int n4) {
  int stride = gridDim.x * blockDim.x;
  for (int i = blockIdx.x * blockDim.x + threadIdx.x; i < n4; i += stride) {
    float4 v = reinterpret_cast<const float4*>(src)[i];
    bf16x4 o = { (bf16)v.x, (bf16)v.y, (bf16)v.z, (bf16)v.w };
    reinterpret_cast<bf16x4*>(dst)[i] = o;
  }
}

// ---------------- RoPE cos/sin table: tab[s][i] = {cos, sin} ----------------
__global__ void rope_table_k(float* __restrict__ tab) {
  int idx = blockIdx.x * blockDim.x + threadIdx.x;
  if (idx >= S_ * (HD_ / 2)) return;
  int pos = idx >> 6, i = idx & 63;
  float inv = powf(10000.0f, -(2.0f * i) / (float)HD_);
  float ang = (float)pos * inv;
  tab[2 * idx]     = cosf(ang);
  tab[2 * idx + 1] = sinf(ang);
}

// ---------------- bf16 GEMM: C[M,N] = A[M,K] * Bt[N,K]^T ----------------
// OUTF=0: bf16 out row-major [M][N]
// OUTF=1: f32 out + bias
// OUTF=2: bf16 out transposed to vt[b][h][d][s]  (N==DM, M==B_*S_)
// OUTF=3: bf16 out row-major with fused RoPE (pairs via shfl_xor(1)) * scale
template<int OUTF>
__global__ __launch_bounds__(256, 2)
void gemm_bt(const bf16* __restrict__ A, const bf16* __restrict__ Bt,
             bf16* __restrict__ Cb, float* __restrict__ Cf,
             const float* __restrict__ bias, const float* __restrict__ tab,
             float scale, int M, int N, int K) {
  __shared__ bf16 As[128][32];
  __shared__ bf16 Bs[128][32];
  const int tid = threadIdx.x;
  const int w = tid >> 6, l = tid & 63;
  const int row0 = blockIdx.x * 128, col0 = blockIdx.y * 128;
  const int wm = (w >> 1) * 64, wn = (w & 1) * 64;
  const int lr = l & 15, lg = l >> 4;
  f32x4 acc[4][4] = {};
  for (int kt = 0; kt < K; kt += 32) {
    __syncthreads();
#pragma unroll
    for (int i = 0; i < 2; ++i) {
      int eo = (i * 4096 + w * 1024) / 2 + l * 8;  // element offset incl. lane
      int r = eo >> 5, c = eo & 31;
      gload_lds16(A  + (size_t)(row0 + r) * K + kt + c, &As[0][0] + i * 2048 + w * 512);
      gload_lds16(Bt + (size_t)(col0 + r) * K + kt + c, &Bs[0][0] + i * 2048 + w * 512);
    }
    asm volatile("s_waitcnt vmcnt(0)" ::: "memory");
    __syncthreads();
    bf16x8 af[4], bfr[4];
#pragma unroll
    for (int mi = 0; mi < 4; ++mi)
      af[mi] = *reinterpret_cast<const bf16x8*>(&As[wm + mi * 16 + lr][lg * 8]);
#pragma unroll
    for (int ni = 0; ni < 4; ++ni)
      bfr[ni] = *reinterpret_cast<const bf16x8*>(&Bs[wn + ni * 16 + lr][lg * 8]);
#pragma unroll
    for (int mi = 0; mi < 4; ++mi)
#pragma unroll
      for (int ni = 0; ni < 4; ++ni)
        acc[mi][ni] = __builtin_amdgcn_mfma_f32_16x16x32_bf16(af[mi], bfr[ni], acc[mi][ni], 0, 0, 0);
  }
#pragma unroll
  for (int mi = 0; mi < 4; ++mi) {
    int rb = row0 + wm + mi * 16 + lg * 4;
#pragma unroll
    for (int ni = 0; ni < 4; ++ni) {
      int cc = col0 + wn + ni * 16 + lr;
      if (OUTF == 2) {
        // transposed V write: vt[b][h][d][s], 4 s-contiguous per lane
        int bb = rb >> 11, s = rb & 2047;
        int hh = cc >> 7, dd = cc & 127;
        bf16x4 pack = { (bf16)acc[mi][ni][0], (bf16)acc[mi][ni][1],
                        (bf16)acc[mi][ni][2], (bf16)acc[mi][ni][3] };
        *reinterpret_cast<bf16x4*>(Cb + (((size_t)(bb * H_ + hh) * HD_ + dd) << 11) + s) = pack;
      } else if (OUTF == 3) {
        // fused RoPE: lanes lr even hold x0 (col even), odd hold x1
        int i2 = (cc & 127) >> 1;
        float sgn = (lr & 1) ? 1.0f : -1.0f;
#pragma unroll
        for (int j = 0; j < 4; ++j) {
          float own = acc[mi][ni][j];
          float par = __shfl_xor(own, 1);
          int s = (rb + j) & (S_ - 1);
          float2 cs = reinterpret_cast<const float2*>(tab)[s * 64 + i2];
          float outv = (own * cs.x + sgn * par * cs.y) * scale;
          Cb[(size_t)(rb + j) * N + cc] = (bf16)outv;
        }
      } else {
#pragma unroll
        for (int j = 0; j < 4; ++j) {
          size_t off = (size_t)(rb + j) * N + cc;
          if (OUTF == 1) Cf[off] = acc[mi][ni][j] + bias[cc];
          else           Cb[off] = (bf16)acc[mi][ni][j];
        }
      }
    }
  }
}

// ---------------- causal flash attention ----------------
// block = 512 thr (8 waves). Paired q-tiles: block bx does q-tiles (15-bx) and bx
// -> uniform 34 KV-tiles/block; grid 8x16x4 = 512 = exactly 2 blocks/CU.
// Swapped QK^T: sc = mfma(K,Q) so each lane owns P-row q=lr (in-register reduce).
// K staged [64][128] XOR-swizzled; V pre-transposed vt[b][h][d][s], staged swizzled.
// Double-buffered, counted vmcnt(4). Q pre-scaled+roped. Output ctx bf16 [b,s,h*HD+d].
__global__ __launch_bounds__(512, 4)
void attn_fwd(const bf16* __restrict__ Q, const bf16* __restrict__ K,
              const bf16* __restrict__ Vt, bf16* __restrict__ O) {
  __shared__ bf16 Ks[2][64 * 128];
  __shared__ bf16 Vs[2][128 * 64];
  __shared__ bf16 Ps[8][16 * 64];
  const int tid = threadIdx.x;
  const int w = tid >> 6, l = tid & 63;
  const int lr = l & 15, lg = l >> 4;
  const int bx = blockIdx.x;
  const int h = blockIdx.y, b = blockIdx.z;
  const size_t bbase = (size_t)b * S_ * DM + (size_t)h * HD_;
  const bf16* vtb = Vt + (size_t)(b * H_ + h) * HD_ * S_;

#pragma unroll 1
  for (int pass = 0; pass < 2; ++pass) {
    const int qt = pass ? bx : (15 - bx);
    const int q0 = qt * 128 + w * 16;
    const int ktmax = 2 * qt + 1;

    bf16x8 qf[4];
#pragma unroll
    for (int kb = 0; kb < 4; ++kb)
      qf[kb] = *reinterpret_cast<const bf16x8*>(Q + bbase + (size_t)(q0 + lr) * DM + kb * 32 + lg * 8);

    float m_r = -INFINITY;   // running max for q-row (q0+lr), replicated over lg
    float l_r = 0.f;         // running denom for q-row (q0+lr)
    f32x4 o[8] = {};

    // prologue: stage tile 0 into buf 0 (4 gloads per wave: 2 K + 2 V)
#pragma unroll
    for (int i = 0; i < 2; ++i) {
      int X = w * 2048 + i * 1024 + l * 16;
      int r = X >> 8, scb = (X & 255) ^ ((r & 7) << 4);
      gload_lds16(K + bbase + (size_t)r * DM + (scb >> 1), &Ks[0][(w * 2048 + i * 1024) >> 1]);
    }
#pragma unroll
    for (int i = 0; i < 2; ++i) {
      int X = w * 2048 + i * 1024 + l * 16;
      int d = X >> 7, scb = (X & 127) ^ ((d & 7) << 4);
      gload_lds16(vtb + (size_t)d * S_ + (scb >> 1), &Vs[0][(w * 2048 + i * 1024) >> 1]);
    }

    for (int kt = 0; kt <= ktmax; ++kt) {
      const int buf = kt & 1;
      if (kt < ktmax) {
        const int nk = (kt + 1) * 64;
#pragma unroll
        for (int i = 0; i < 2; ++i) {
          int X = w * 2048 + i * 1024 + l * 16;
          int r = X >> 8, scb = (X & 255) ^ ((r & 7) << 4);
          gload_lds16(K + bbase + (size_t)(nk + r) * DM + (scb >> 1),
                      &Ks[buf ^ 1][(w * 2048 + i * 1024) >> 1]);
        }
#pragma unroll
        for (int i = 0; i < 2; ++i) {
          int X = w * 2048 + i * 1024 + l * 16;
          int d = X >> 7, scb = (X & 127) ^ ((d & 7) << 4);
          gload_lds16(vtb + (size_t)d * S_ + nk + (scb >> 1),
                      &Vs[buf ^ 1][(w * 2048 + i * 1024) >> 1]);
        }
        asm volatile("s_waitcnt vmcnt(4)" ::: "memory");  // current tile done, next in flight
      } else {
        asm volatile("s_waitcnt vmcnt(0)" ::: "memory");
      }
      __builtin_amdgcn_s_barrier();

      // ---- swapped QK^T: sc[cb] = K-block(cb) . Q -> lane holds P[kv][q=lr] ----
      f32x4 sc4[4];
      __builtin_amdgcn_s_setprio(1);
#pragma unroll
      for (int cb = 0; cb < 4; ++cb) {
        sc4[cb] = f32x4{0.f, 0.f, 0.f, 0.f};
        int r = cb * 16 + lr;
#pragma unroll
        for (int kb = 0; kb < 4; ++kb) {
          int off = r * 256 + ((kb * 64 + lg * 16) ^ ((lr & 7) << 4));
          bf16x8 kf = *reinterpret_cast<const bf16x8*>((const char*)Ks[buf] + off);
          sc4[cb] = __builtin_amdgcn_mfma_f32_16x16x32_bf16(kf, qf[kb], sc4[cb], 0, 0, 0);
        }
      }
      __builtin_amdgcn_s_setprio(0);

      // ---- causal mask: kv = kv0 + cb*16 + lg*4 + jj ; q = q0 + lr ----
      const int kv0 = kt * 64;
      if (kv0 + 63 > q0) {
        const int qq = q0 + lr;
#pragma unroll
        for (int cb = 0; cb < 4; ++cb)
#pragma unroll
          for (int jj = 0; jj < 4; ++jj)
            if (kv0 + cb * 16 + lg * 4 + jj > qq) sc4[cb][jj] = -INFINITY;
      }

      // ---- online softmax: row is lane-local; reduce across lg via 2 shfls ----
      float tm = -INFINITY;
#pragma unroll
      for (int cb = 0; cb < 4; ++cb)
#pragma unroll
        for (int jj = 0; jj < 4; ++jj) tm = fmaxf(tm, sc4[cb][jj]);
      tm = fmaxf(tm, __shfl_xor(tm, 16));
      tm = fmaxf(tm, __shfl_xor(tm, 32));
      float mnew = fmaxf(m_r, tm);
      float sc_f = __expf(m_r - mnew);
      m_r = mnew;
      float rs = 0.f;
#pragma unroll
      for (int cb = 0; cb < 4; ++cb)
#pragma unroll
        for (int jj = 0; jj < 4; ++jj) {
          float p = __expf(sc4[cb][jj] - mnew);
          sc4[cb][jj] = p;
          rs += p;
        }
      rs += __shfl_xor(rs, 16);
      rs += __shfl_xor(rs, 32);
      l_r = l_r * sc_f + rs;

      // broadcast scalef from row-lane (lr) layout to o-accumulator layout (lg*4+j)
      float scO[4];
#pragma unroll
      for (int j = 0; j < 4; ++j) scO[j] = __shfl(sc_f, lg * 4 + j);
#pragma unroll
      for (int nb = 0; nb < 8; ++nb)
#pragma unroll
        for (int j = 0; j < 4; ++j) o[nb][j] *= scO[j];

      // ---- P -> LDS: row q=lr, 4 contiguous kv per write (b64, swizzled) ----
#pragma unroll
      for (int cb = 0; cb < 4; ++cb) {
        bf16x4 pk = { (bf16)sc4[cb][0], (bf16)sc4[cb][1], (bf16)sc4[cb][2], (bf16)sc4[cb][3] };
        int off = lr * 128 + ((cb * 32 + lg * 8) ^ ((lr & 7) << 4));
        *reinterpret_cast<bf16x4*>((char*)Ps[w] + off) = pk;
      }

      // ---- PV ----
      bf16x8 pf[2];
#pragma unroll
      for (int kc = 0; kc < 2; ++kc) {
        int off = lr * 128 + ((kc * 64 + lg * 16) ^ ((lr & 7) << 4));
        pf[kc] = *reinterpret_cast<const bf16x8*>((const char*)Ps[w] + off);
      }
      __builtin_amdgcn_s_setprio(1);
#pragma unroll
      for (int nb = 0; nb < 8; ++nb) {
        int d = nb * 16 + lr;
#pragma unroll
        for (int kc = 0; kc < 2; ++kc) {
          int off = d * 128 + ((kc * 64 + lg * 16) ^ ((lr & 7) << 4));
          bf16x8 vf = *reinterpret_cast<const bf16x8*>((const char*)Vs[buf] + off);
          o[nb] = __builtin_amdgcn_mfma_f32_16x16x32_bf16(pf[kc], vf, o[nb], 0, 0, 0);
        }
      }
      __builtin_amdgcn_s_setprio(0);

      asm volatile("s_waitcnt lgkmcnt(0)" ::: "memory");  // all LDS reads of buf retired
      __builtin_amdgcn_s_barrier();                       // before buf is restaged
    }

    // ---- epilogue: broadcast l to o-layout, normalize, store ----
    float lO[4];
#pragma unroll
    for (int j = 0; j < 4; ++j) lO[j] = __shfl(l_r, lg * 4 + j);
#pragma unroll
    for (int j = 0; j < 4; ++j) {
      float inv = 1.0f / lO[j];
      size_t rowoff = bbase + (size_t)(q0 + lg * 4 + j) * DM;
#pragma unroll
      for (int nb = 0; nb < 8; ++nb)
        O[rowoff + nb * 16 + lr] = (bf16)(o[nb][j] * inv);
    }
  }
}

extern "C" void kernel_launch(void* const* d_in, const int* in_sizes, int n_in,
                              void* d_out, int out_size, void* d_ws, size_t ws_size,
                              hipStream_t stream) {
  const float* x  = (const float*)d_in[0];
  const float* Wq = (const float*)d_in[1];
  const float* Wk = (const float*)d_in[2];
  const float* Wv = (const float*)d_in[3];
  const float* Wo = (const float*)d_in[4];
  const float* bo = (const float*)d_in[5];
  float* out = (float*)d_out;

  const size_t NX = (size_t)B_ * S_ * DM;  // 16,777,216
  const size_t NW = (size_t)DM * DM;       //  4,194,304
  char* ws = (char*)d_ws;
  bf16* xb   = (bf16*)ws; ws += NX * 2;
  bf16* wqb  = (bf16*)ws; ws += NW * 2;
  bf16* wkb  = (bf16*)ws; ws += NW * 2;
  bf16* wvb  = (bf16*)ws; ws += NW * 2;
  bf16* wob  = (bf16*)ws; ws += NW * 2;
  bf16* qb   = (bf16*)ws; ws += NX * 2;
  bf16* kb   = (bf16*)ws; ws += NX * 2;
  bf16* vt   = (bf16*)ws; ws += NX * 2;   // V pre-transposed [B][H][HD][S]
  bf16* ctxb = (bf16*)ws; ws += NX * 2;
  float* tab = (float*)ws; ws += (size_t)S_ * 64 * 2 * sizeof(float);

  cast_f32_bf16<<<(int)((NX / 4 + 255) / 256), 256, 0, stream>>>(x, xb, (int)(NX / 4));
  cast_f32_bf16<<<(int)((NW / 4 + 255) / 256), 256, 0, stream>>>(Wq, wqb, (int)(NW / 4));
  cast_f32_bf16<<<(int)((NW / 4 + 255) / 256), 256, 0, stream>>>(Wk, wkb, (int)(NW / 4));
  cast_f32_bf16<<<(int)((NW / 4 + 255) / 256), 256, 0, stream>>>(Wv, wvb, (int)(NW / 4));
  cast_f32_bf16<<<(int)((NW / 4 + 255) / 256), 256, 0, stream>>>(Wo, wob, (int)(NW / 4));
  rope_table_k<<<(S_ * 64 + 255) / 256, 256, 0, stream>>>(tab);

  const int M = B_ * S_;
  dim3 gg(M / 128, DM / 128);
  // Q/K with fused RoPE (Q also folds 1/sqrt(HD)); V transposed
  gemm_bt<3><<<gg, 256, 0, stream>>>(xb, wqb, qb, nullptr, nullptr, tab, 0.08838834764831845f, M, DM, DM);
  gemm_bt<3><<<gg, 256, 0, stream>>>(xb, wkb, kb, nullptr, nullptr, tab, 1.0f, M, DM, DM);
  gemm_bt<2><<<gg, 256, 0, stream>>>(xb, wvb, vt, nullptr, nullptr, nullptr, 0.f, M, DM, DM);

  attn_fwd<<<dim3(8, H_, B_), 512, 0, stream>>>(qb, kb, vt, ctxb);

  gemm_bt<1><<<gg, 256, 0, stream>>>(ctxb, wob, nullptr, out, bo, nullptr, 0.f, M, DM, DM);
}

// Round 5
// 472.576 us; speedup vs baseline: 2.0898x; 1.0306x over previous
//
#include <hip/hip_runtime.h>
#include <hip/hip_bf16.h>
#include <math.h>

#define B_  4
#define S_  2048
#define DM  2048
#define H_  16
#define HD_ 128

typedef __bf16 bf16;
typedef __bf16 bf16x4 __attribute__((ext_vector_type(4)));
typedef __bf16 bf16x8 __attribute__((ext_vector_type(8)));
typedef float  f32x4  __attribute__((ext_vector_type(4)));

__device__ __forceinline__ void gload_lds16(const bf16* g, bf16* l) {
  __builtin_amdgcn_global_load_lds(
      (const __attribute__((address_space(1))) void*)g,
      (__attribute__((address_space(3))) void*)l, 16, 0, 0);
}

// ---------------- cast fp32 -> bf16 (vectorized) ----------------
__global__ void cast_f32_bf16(const float* __restrict__ src, bf16* __restrict__ dst, int n4) {
  int stride = gridDim.x * blockDim.x;
  for (int i = blockIdx.x * blockDim.x + threadIdx.x; i < n4; i += stride) {
    float4 v = reinterpret_cast<const float4*>(src)[i];
    bf16x4 o = { (bf16)v.x, (bf16)v.y, (bf16)v.z, (bf16)v.w };
    reinterpret_cast<bf16x4*>(dst)[i] = o;
  }
}

// ---------------- RoPE cos/sin table: tab[s][i] = {cos, sin} ----------------
__global__ void rope_table_k(float* __restrict__ tab) {
  int idx = blockIdx.x * blockDim.x + threadIdx.x;
  if (idx >= S_ * (HD_ / 2)) return;
  int pos = idx >> 6, i = idx & 63;
  float inv = powf(10000.0f, -(2.0f * i) / (float)HD_);
  float ang = (float)pos * inv;
  tab[2 * idx]     = cosf(ang);
  tab[2 * idx + 1] = sinf(ang);
}

// ---------------- pipelined bf16 GEMM: C[M,N] = A[M,K] * Bt[N,K]^T ----------------
// BM=512, BN=128, BK=32. 8 waves as 4M x 2N (wave tile 128x64).
// Triple-buffered LDS (3 x 40KB = 120KB, 1 block/CU), 2-tile lookahead,
// counted vmcnt(10) (never 0 in main loop). XOR swizzle ((row>>1)&3)<<4 on
// byte offsets, applied to pre-swizzled global source + swizzled ds_read.
// EPI=0: fused QKV epilogue (col region 0: rope-Q, 1: rope-K, 2: transpose-V)
// EPI=1: f32 out + bias
template<int EPI>
__global__ __launch_bounds__(512, 2)
void gemm512(const bf16* __restrict__ A, const bf16* __restrict__ Bt,
             bf16* __restrict__ Oq, bf16* __restrict__ Ok, bf16* __restrict__ Ovt,
             float* __restrict__ Cf, const float* __restrict__ bias,
             const float* __restrict__ tab, int N, int K) {
  __shared__ bf16 lds[61440];  // 3 buffers x (A 512x32 + B 128x32) bf16
  const int tid = threadIdx.x;
  const int w = tid >> 6, l = tid & 63;
  const int lr = l & 15, lg = l >> 4;
  const int row0 = blockIdx.y * 512, col0 = blockIdx.x * 128;
  const int wm = w >> 1, wn = w & 1;
  const int NT = K / 32;

  // stage tile t into buffer c: A 4 gloads/wave + B 1 gload/wave (5 total)
  auto stage = [&](int t, int c) {
    const bf16* Ab = A + (size_t)row0 * K + t * 32;
    const bf16* Bb = Bt + (size_t)col0 * K + t * 32;
    bf16* base = lds + c * 20480;
#pragma unroll
    for (int i = 0; i < 4; ++i) {
      int D = w * 4096 + i * 1024 + l * 16;             // dest byte in A region
      int r = D >> 6;
      int gk = ((D & 63) ^ (((r >> 1) & 3) << 4)) >> 1; // pre-swizzled source k
      gload_lds16(Ab + (size_t)r * K + gk, base + ((w * 4096 + i * 1024) >> 1));
    }
    {
      int D = w * 1024 + l * 16;                        // dest byte in B region
      int r = D >> 6;
      int gk = ((D & 63) ^ (((r >> 1) & 3) << 4)) >> 1;
      gload_lds16(Bb + (size_t)r * K + gk, base + 16384 + ((w * 1024) >> 1));
    }
  };

  // invariant swizzled LDS byte offsets for the 12 fragment reads
  int offA[8], offB[4];
#pragma unroll
  for (int mi = 0; mi < 8; ++mi) {
    int r = wm * 128 + mi * 16 + lr;
    offA[mi] = r * 64 + ((lg * 16) ^ (((r >> 1) & 3) << 4));
  }
#pragma unroll
  for (int ni = 0; ni < 4; ++ni) {
    int r = wn * 64 + ni * 16 + lr;
    offB[ni] = 32768 + r * 64 + ((lg * 16) ^ (((r >> 1) & 3) << 4));
  }

  f32x4 acc[8][4] = {};
  stage(0, 0);
  stage(1, 1);

  for (int t = 0; t < NT; ++t) {
    const int c = t % 3;
    if (t + 2 < NT) {
      stage(t + 2, (t + 2) % 3);
      asm volatile("s_waitcnt vmcnt(10)" ::: "memory");  // tile t retired; t+1,t+2 in flight
    } else if (t + 1 < NT) {
      asm volatile("s_waitcnt vmcnt(5)" ::: "memory");
    } else {
      asm volatile("s_waitcnt vmcnt(0)" ::: "memory");
    }
    __builtin_amdgcn_s_barrier();

    const char* bb = (const char*)lds + c * 40960;
    bf16x8 af[8], bfr[4];
#pragma unroll
    for (int mi = 0; mi < 8; ++mi) af[mi] = *reinterpret_cast<const bf16x8*>(bb + offA[mi]);
#pragma unroll
    for (int ni = 0; ni < 4; ++ni) bfr[ni] = *reinterpret_cast<const bf16x8*>(bb + offB[ni]);

    __builtin_amdgcn_s_setprio(1);
#pragma unroll
    for (int mi = 0; mi < 8; ++mi)
#pragma unroll
      for (int ni = 0; ni < 4; ++ni)
        acc[mi][ni] = __builtin_amdgcn_mfma_f32_16x16x32_bf16(af[mi], bfr[ni], acc[mi][ni], 0, 0, 0);
    __builtin_amdgcn_s_setprio(0);
    __builtin_amdgcn_s_barrier();   // all waves' reads of buf c done before restage at t+1
  }

  // ---- epilogue ----
#pragma unroll
  for (int mi = 0; mi < 8; ++mi) {
    int rb = row0 + wm * 128 + mi * 16 + lg * 4;
#pragma unroll
    for (int ni = 0; ni < 4; ++ni) {
      int gc = col0 + wn * 64 + ni * 16 + lr;
      if (EPI == 1) {
#pragma unroll
        for (int j = 0; j < 4; ++j)
          Cf[(size_t)(rb + j) * N + gc] = acc[mi][ni][j] + bias[gc];
      } else {
        int reg = col0 >> 11;     // uniform per block: 0=Q, 1=K, 2=V
        int cc = gc & 2047;
        if (reg == 2) {
          // transposed V write: vt[b][h][d][s], 4 s-contiguous per lane
          int bb2 = rb >> 11, s = rb & 2047;
          int hh = cc >> 7, dd = cc & 127;
          bf16x4 pack = { (bf16)acc[mi][ni][0], (bf16)acc[mi][ni][1],
                          (bf16)acc[mi][ni][2], (bf16)acc[mi][ni][3] };
          *reinterpret_cast<bf16x4*>(Ovt + (((size_t)(bb2 * H_ + hh) * HD_ + dd) << 11) + s) = pack;
        } else {
          bf16* Dst = (reg == 0) ? Oq : Ok;
          float scale = (reg == 0) ? 0.08838834764831845f : 1.0f;
          int i2 = (cc & 127) >> 1;
          float sgn = (lr & 1) ? 1.0f : -1.0f;
#pragma unroll
          for (int j = 0; j < 4; ++j) {
            float own = acc[mi][ni][j];
            float par = __shfl_xor(own, 1);
            int s = (rb + j) & (S_ - 1);
            float2 cs = reinterpret_cast<const float2*>(tab)[s * 64 + i2];
            Dst[(size_t)(rb + j) * 2048 + cc] = (bf16)((own * cs.x + sgn * par * cs.y) * scale);
          }
        }
      }
    }
  }
}

// ---------------- causal flash attention (unchanged from R4) ----------------
__global__ __launch_bounds__(512, 4)
void attn_fwd(const bf16* __restrict__ Q, const bf16* __restrict__ K,
              const bf16* __restrict__ Vt, bf16* __restrict__ O) {
  __shared__ bf16 Ks[2][64 * 128];
  __shared__ bf16 Vs[2][128 * 64];
  __shared__ bf16 Ps[8][16 * 64];
  const int tid = threadIdx.x;
  const int w = tid >> 6, l = tid & 63;
  const int lr = l & 15, lg = l >> 4;
  const int bx = blockIdx.x;
  const int h = blockIdx.y, b = blockIdx.z;
  const size_t bbase = (size_t)b * S_ * DM + (size_t)h * HD_;
  const bf16* vtb = Vt + (size_t)(b * H_ + h) * HD_ * S_;

#pragma unroll 1
  for (int pass = 0; pass < 2; ++pass) {
    const int qt = pass ? bx : (15 - bx);
    const int q0 = qt * 128 + w * 16;
    const int ktmax = 2 * qt + 1;

    bf16x8 qf[4];
#pragma unroll
    for (int kb = 0; kb < 4; ++kb)
      qf[kb] = *reinterpret_cast<const bf16x8*>(Q + bbase + (size_t)(q0 + lr) * DM + kb * 32 + lg * 8);

    float m_r = -INFINITY;
    float l_r = 0.f;
    f32x4 o[8] = {};

#pragma unroll
    for (int i = 0; i < 2; ++i) {
      int X = w * 2048 + i * 1024 + l * 16;
      int r = X >> 8, scb = (X & 255) ^ ((r & 7) << 4);
      gload_lds16(K + bbase + (size_t)r * DM + (scb >> 1), &Ks[0][(w * 2048 + i * 1024) >> 1]);
    }
#pragma unroll
    for (int i = 0; i < 2; ++i) {
      int X = w * 2048 + i * 1024 + l * 16;
      int d = X >> 7, scb = (X & 127) ^ ((d & 7) << 4);
      gload_lds16(vtb + (size_t)d * S_ + (scb >> 1), &Vs[0][(w * 2048 + i * 1024) >> 1]);
    }

    for (int kt = 0; kt <= ktmax; ++kt) {
      const int buf = kt & 1;
      if (kt < ktmax) {
        const int nk = (kt + 1) * 64;
#pragma unroll
        for (int i = 0; i < 2; ++i) {
          int X = w * 2048 + i * 1024 + l * 16;
          int r = X >> 8, scb = (X & 255) ^ ((r & 7) << 4);
          gload_lds16(K + bbase + (size_t)(nk + r) * DM + (scb >> 1),
                      &Ks[buf ^ 1][(w * 2048 + i * 1024) >> 1]);
        }
#pragma unroll
        for (int i = 0; i < 2; ++i) {
          int X = w * 2048 + i * 1024 + l * 16;
          int d = X >> 7, scb = (X & 127) ^ ((d & 7) << 4);
          gload_lds16(vtb + (size_t)d * S_ + nk + (scb >> 1),
                      &Vs[buf ^ 1][(w * 2048 + i * 1024) >> 1]);
        }
        asm volatile("s_waitcnt vmcnt(4)" ::: "memory");
      } else {
        asm volatile("s_waitcnt vmcnt(0)" ::: "memory");
      }
      __builtin_amdgcn_s_barrier();

      f32x4 sc4[4];
      __builtin_amdgcn_s_setprio(1);
#pragma unroll
      for (int cb = 0; cb < 4; ++cb) {
        sc4[cb] = f32x4{0.f, 0.f, 0.f, 0.f};
        int r = cb * 16 + lr;
#pragma unroll
        for (int kb = 0; kb < 4; ++kb) {
          int off = r * 256 + ((kb * 64 + lg * 16) ^ ((lr & 7) << 4));
          bf16x8 kf = *reinterpret_cast<const bf16x8*>((const char*)Ks[buf] + off);
          sc4[cb] = __builtin_amdgcn_mfma_f32_16x16x32_bf16(kf, qf[kb], sc4[cb], 0, 0, 0);
        }
      }
      __builtin_amdgcn_s_setprio(0);

      const int kv0 = kt * 64;
      if (kv0 + 63 > q0) {
        const int qq = q0 + lr;
#pragma unroll
        for (int cb = 0; cb < 4; ++cb)
#pragma unroll
          for (int jj = 0; jj < 4; ++jj)
            if (kv0 + cb * 16 + lg * 4 + jj > qq) sc4[cb][jj] = -INFINITY;
      }

      float tm = -INFINITY;
#pragma unroll
      for (int cb = 0; cb < 4; ++cb)
#pragma unroll
        for (int jj = 0; jj < 4; ++jj) tm = fmaxf(tm, sc4[cb][jj]);
      tm = fmaxf(tm, __shfl_xor(tm, 16));
      tm = fmaxf(tm, __shfl_xor(tm, 32));
      float mnew = fmaxf(m_r, tm);
      float sc_f = __expf(m_r - mnew);
      m_r = mnew;
      float rs = 0.f;
#pragma unroll
      for (int cb = 0; cb < 4; ++cb)
#pragma unroll
        for (int jj = 0; jj < 4; ++jj) {
          float p = __expf(sc4[cb][jj] - mnew);
          sc4[cb][jj] = p;
          rs += p;
        }
      rs += __shfl_xor(rs, 16);
      rs += __shfl_xor(rs, 32);
      l_r = l_r * sc_f + rs;

      float scO[4];
#pragma unroll
      for (int j = 0; j < 4; ++j) scO[j] = __shfl(sc_f, lg * 4 + j);
#pragma unroll
      for (int nb = 0; nb < 8; ++nb)
#pragma unroll
        for (int j = 0; j < 4; ++j) o[nb][j] *= scO[j];

#pragma unroll
      for (int cb = 0; cb < 4; ++cb) {
        bf16x4 pk = { (bf16)sc4[cb][0], (bf16)sc4[cb][1], (bf16)sc4[cb][2], (bf16)sc4[cb][3] };
        int off = lr * 128 + ((cb * 32 + lg * 8) ^ ((lr & 7) << 4));
        *reinterpret_cast<bf16x4*>((char*)Ps[w] + off) = pk;
      }

      bf16x8 pf[2];
#pragma unroll
      for (int kc = 0; kc < 2; ++kc) {
        int off = lr * 128 + ((kc * 64 + lg * 16) ^ ((lr & 7) << 4));
        pf[kc] = *reinterpret_cast<const bf16x8*>((const char*)Ps[w] + off);
      }
      __builtin_amdgcn_s_setprio(1);
#pragma unroll
      for (int nb = 0; nb < 8; ++nb) {
        int d = nb * 16 + lr;
#pragma unroll
        for (int kc = 0; kc < 2; ++kc) {
          int off = d * 128 + ((kc * 64 + lg * 16) ^ ((lr & 7) << 4));
          bf16x8 vf = *reinterpret_cast<const bf16x8*>((const char*)Vs[buf] + off);
          o[nb] = __builtin_amdgcn_mfma_f32_16x16x32_bf16(pf[kc], vf, o[nb], 0, 0, 0);
        }
      }
      __builtin_amdgcn_s_setprio(0);

      asm volatile("s_waitcnt lgkmcnt(0)" ::: "memory");
      __builtin_amdgcn_s_barrier();
    }

    float lO[4];
#pragma unroll
    for (int j = 0; j < 4; ++j) lO[j] = __shfl(l_r, lg * 4 + j);
#pragma unroll
    for (int j = 0; j < 4; ++j) {
      float inv = 1.0f / lO[j];
      size_t rowoff = bbase + (size_t)(q0 + lg * 4 + j) * DM;
#pragma unroll
      for (int nb = 0; nb < 8; ++nb)
        O[rowoff + nb * 16 + lr] = (bf16)(o[nb][j] * inv);
    }
  }
}

extern "C" void kernel_launch(void* const* d_in, const int* in_sizes, int n_in,
                              void* d_out, int out_size, void* d_ws, size_t ws_size,
                              hipStream_t stream) {
  const float* x  = (const float*)d_in[0];
  const float* Wq = (const float*)d_in[1];
  const float* Wk = (const float*)d_in[2];
  const float* Wv = (const float*)d_in[3];
  const float* Wo = (const float*)d_in[4];
  const float* bo = (const float*)d_in[5];
  float* out = (float*)d_out;

  const size_t NX = (size_t)B_ * S_ * DM;  // 16,777,216
  const size_t NW = (size_t)DM * DM;       //  4,194,304
  char* ws = (char*)d_ws;
  bf16* xb   = (bf16*)ws; ws += NX * 2;
  bf16* wqkv = (bf16*)ws; ws += 3 * NW * 2;  // [Wq;Wk;Wv] as one [6144][2048]
  bf16* wob  = (bf16*)ws; ws += NW * 2;
  bf16* qb   = (bf16*)ws; ws += NX * 2;
  bf16* kb   = (bf16*)ws; ws += NX * 2;
  bf16* vt   = (bf16*)ws; ws += NX * 2;   // V pre-transposed [B][H][HD][S]
  bf16* ctxb = (bf16*)ws; ws += NX * 2;
  float* tab = (float*)ws; ws += (size_t)S_ * 64 * 2 * sizeof(float);

  cast_f32_bf16<<<(int)((NX / 4 + 255) / 256), 256, 0, stream>>>(x, xb, (int)(NX / 4));
  cast_f32_bf16<<<(int)((NW / 4 + 255) / 256), 256, 0, stream>>>(Wq, wqkv, (int)(NW / 4));
  cast_f32_bf16<<<(int)((NW / 4 + 255) / 256), 256, 0, stream>>>(Wk, wqkv + NW, (int)(NW / 4));
  cast_f32_bf16<<<(int)((NW / 4 + 255) / 256), 256, 0, stream>>>(Wv, wqkv + 2 * NW, (int)(NW / 4));
  cast_f32_bf16<<<(int)((NW / 4 + 255) / 256), 256, 0, stream>>>(Wo, wob, (int)(NW / 4));
  rope_table_k<<<(S_ * 64 + 255) / 256, 256, 0, stream>>>(tab);

  const int M = B_ * S_;
  // fused QKV projection + RoPE + V-transpose: C[8192][6144]
  gemm512<0><<<dim3(3 * DM / 128, M / 512), 512, 0, stream>>>(
      xb, wqkv, qb, kb, vt, nullptr, nullptr, tab, 3 * DM, DM);

  attn_fwd<<<dim3(8, H_, B_), 512, 0, stream>>>(qb, kb, vt, ctxb);

  // output projection + bias (f32 out)
  gemm512<1><<<dim3(DM / 128, M / 512), 512, 0, stream>>>(
      ctxb, wob, nullptr, nullptr, nullptr, out, bo, nullptr, DM, DM);
}

// Round 6
// 438.765 us; speedup vs baseline: 2.2508x; 1.0771x over previous
//
#include <hip/hip_runtime.h>
#include <hip/hip_bf16.h>
#include <math.h>

#define B_  4
#define S_  2048
#define DM  2048
#define H_  16
#define HD_ 128

typedef __bf16 bf16;
typedef __bf16 bf16x4 __attribute__((ext_vector_type(4)));
typedef __bf16 bf16x8 __attribute__((ext_vector_type(8)));
typedef float  f32x4  __attribute__((ext_vector_type(4)));

__device__ __forceinline__ void gload_lds16(const bf16* g, bf16* l) {
  __builtin_amdgcn_global_load_lds(
      (const __attribute__((address_space(1))) void*)g,
      (__attribute__((address_space(3))) void*)l, 16, 0, 0);
}

// ---------------- cast fp32 -> bf16 (vectorized) ----------------
__global__ void cast_f32_bf16(const float* __restrict__ src, bf16* __restrict__ dst, int n4) {
  int stride = gridDim.x * blockDim.x;
  for (int i = blockIdx.x * blockDim.x + threadIdx.x; i < n4; i += stride) {
    float4 v = reinterpret_cast<const float4*>(src)[i];
    bf16x4 o = { (bf16)v.x, (bf16)v.y, (bf16)v.z, (bf16)v.w };
    reinterpret_cast<bf16x4*>(dst)[i] = o;
  }
}

// ---------------- RoPE cos/sin table: tab[s][i] = {cos, sin} ----------------
__global__ void rope_table_k(float* __restrict__ tab) {
  int idx = blockIdx.x * blockDim.x + threadIdx.x;
  if (idx >= S_ * (HD_ / 2)) return;
  int pos = idx >> 6, i = idx & 63;
  float inv = powf(10000.0f, -(2.0f * i) / (float)HD_);
  float ang = (float)pos * inv;
  tab[2 * idx]     = cosf(ang);
  tab[2 * idx + 1] = sinf(ang);
}

// ---------------- phase-split bf16 GEMM: C[M,N] = A[M,K] * Bt[N,K]^T ----------------
// BM=BN=256, BK=64, 8 waves (2M x 4N, wave tile 128x64). Two 64KB buffers,
// K-half-slot layout [kh][256 r][32 k] so global_load_lds dest stays linear.
// 4 phases per K-tile = (qm,kh); each: 8 ds_read_b128 + 2 gload_lds + barrier +
// 16 MFMA (setprio). Rolling stage: ph0->A-Khi(kt+1), ph1->B-Khi(kt+1),
// ph2->A-Klo(kt+2), ph3->B-Klo(kt+2). Gates vmcnt(8)+barrier at ph0/ph2 only.
// Swizzle byte^=((r>>1)&3)<<4 within 64B rows (source-pre-swizzled + read-swizzled).
// EPI=0: fused QKV epilogue (col region 0: rope-Q, 1: rope-K, 2: transpose-V)
// EPI=1: f32 out + bias
template<int EPI>
__global__ __launch_bounds__(512, 2)
void gemm8p(const bf16* __restrict__ A, const bf16* __restrict__ Bt,
            bf16* __restrict__ Oq, bf16* __restrict__ Ok, bf16* __restrict__ Ovt,
            float* __restrict__ Cf, const float* __restrict__ bias,
            const float* __restrict__ tab, int N, int K) {
  __shared__ char lds[131072];  // buf p @ p*65536: A [2kh][256][64B] , B @ +32768 same
  const int tid = threadIdx.x;
  const int w = tid >> 6, l = tid & 63;
  const int lr = l & 15, lg = l >> 4;
  const int wm = w >> 2, wn = w & 3;            // 2M x 4N wave grid
  const int row0 = blockIdx.y * 256, col0 = blockIdx.x * 256;
  const int NT = K >> 6;                        // K-tiles of 64

  // stage one 16KB K-half slot of K-tile kt2 (isB: operand, kh: K-half)
  auto stageSlot = [&](int isB, int kh, int kt2) {
    const bf16* src = isB ? (Bt + (size_t)col0 * K) : (A + (size_t)row0 * K);
    char* dstbase = (char*)lds + (kt2 & 1) * 65536 + isB * 32768 + kh * 16384;
    const int kcol = kt2 * 64 + kh * 32;
#pragma unroll
    for (int u = 0; u < 2; ++u) {
      int D = w * 2048 + u * 1024 + l * 16;     // byte within slot
      int r = D >> 6, cb = D & 63;
      int sc = cb ^ (((r >> 1) & 3) << 4);      // pre-swizzled source col byte
      gload_lds16(src + (size_t)r * K + kcol + (sc >> 1),
                  (bf16*)(dstbase + w * 2048 + u * 1024));
    }
  };

  // fragment byte offsets within a buffer (kh=0; +16384 for kh=1)
  const int swzt = ((lr >> 1) & 3) << 4;
  int offA[2][4], offB[4];
#pragma unroll
  for (int qm = 0; qm < 2; ++qm)
#pragma unroll
    for (int mi = 0; mi < 4; ++mi) {
      int r = wm * 128 + qm * 64 + mi * 16 + lr;
      offA[qm][mi] = r * 64 + ((lg * 16) ^ swzt);
    }
#pragma unroll
  for (int ni = 0; ni < 4; ++ni) {
    int r = wn * 64 + ni * 16 + lr;
    offB[ni] = 32768 + r * 64 + ((lg * 16) ^ swzt);
  }

  f32x4 acc[8][4] = {};

  // prologue: 6 slots = K-tile 0 fully + K-tile 1's Klo pair (12 loads)
  stageSlot(0, 0, 0); stageSlot(1, 0, 0);   // ~(-2,2) (-2,3)
  stageSlot(0, 1, 0); stageSlot(1, 1, 0);   // ~(-1,0) (-1,1)
  if (NT > 1) { stageSlot(0, 0, 1); stageSlot(1, 0, 1); }  // ~(-1,2) (-1,3)

#pragma unroll 1
  for (int kt = 0; kt < NT; ++kt) {
    const char* bufb = (const char*)lds + (kt & 1) * 65536;
#pragma unroll
    for (int q = 0; q < 4; ++q) {
      const int qm = q & 1 ? 1 : 0;            // phase->(qm,kh): 0:(0,0) 1:(1,0) 2:(0,1) 3:(1,1)
      const int kh = q >> 1;
      const int qmm = (q == 1 || q == 3) ? 1 : 0;
      // ---- gate (before the ds_reads that consume freshly staged slots) ----
      if (q == 0) {
        if (kt + 1 < NT) asm volatile("s_waitcnt vmcnt(8)" ::: "memory");
        else             asm volatile("s_waitcnt vmcnt(4)" ::: "memory");
        __builtin_amdgcn_s_barrier();
      } else if (q == 2) {
        if (kt + 1 < NT) asm volatile("s_waitcnt vmcnt(8)" ::: "memory");
        else             asm volatile("s_waitcnt vmcnt(0)" ::: "memory");
        __builtin_amdgcn_s_barrier();
      }
      // ---- ds_read fragments for this phase ----
      const char* bb = bufb + kh * 16384;
      bf16x8 af[4], bfr[4];
#pragma unroll
      for (int mi = 0; mi < 4; ++mi)
        af[mi] = *reinterpret_cast<const bf16x8*>(bb + offA[qmm][mi]);
#pragma unroll
      for (int ni = 0; ni < 4; ++ni)
        bfr[ni] = *reinterpret_cast<const bf16x8*>(bb + offB[ni]);
      // ---- rolling stage (2 gloads) ----
      if (q < 2) { if (kt + 1 < NT) stageSlot(q & 1, 1, kt + 1); }
      else       { if (kt + 2 < NT) stageSlot(q & 1, 0, kt + 2); }
      __builtin_amdgcn_s_barrier();
      asm volatile("s_waitcnt lgkmcnt(0)" ::: "memory");
      // ---- 16 MFMA ----
      __builtin_amdgcn_s_setprio(1);
#pragma unroll
      for (int mi = 0; mi < 4; ++mi)
#pragma unroll
        for (int ni = 0; ni < 4; ++ni)
          acc[qmm * 4 + mi][ni] =
              __builtin_amdgcn_mfma_f32_16x16x32_bf16(af[mi], bfr[ni], acc[qmm * 4 + mi][ni], 0, 0, 0);
      __builtin_amdgcn_s_setprio(0);
    }
  }

  // ---- epilogue ----
#pragma unroll
  for (int ai = 0; ai < 8; ++ai) {
    int rb = row0 + wm * 128 + ai * 16 + lg * 4;
#pragma unroll
    for (int ni = 0; ni < 4; ++ni) {
      int gc = col0 + wn * 64 + ni * 16 + lr;
      if (EPI == 1) {
#pragma unroll
        for (int j = 0; j < 4; ++j)
          Cf[(size_t)(rb + j) * N + gc] = acc[ai][ni][j] + bias[gc];
      } else {
        int reg = col0 >> 11;     // uniform per block: 0=Q, 1=K, 2=V
        int cc = gc & 2047;
        if (reg == 2) {
          // transposed V write: vt[b][h][d][s], 4 s-contiguous per lane
          int bb2 = rb >> 11, s = rb & 2047;
          int hh = cc >> 7, dd = cc & 127;
          bf16x4 pack = { (bf16)acc[ai][ni][0], (bf16)acc[ai][ni][1],
                          (bf16)acc[ai][ni][2], (bf16)acc[ai][ni][3] };
          *reinterpret_cast<bf16x4*>(Ovt + (((size_t)(bb2 * H_ + hh) * HD_ + dd) << 11) + s) = pack;
        } else {
          bf16* Dst = (reg == 0) ? Oq : Ok;
          float scale = (reg == 0) ? 0.08838834764831845f : 1.0f;
          int i2 = (cc & 127) >> 1;
          float sgn = (lr & 1) ? 1.0f : -1.0f;
#pragma unroll
          for (int j = 0; j < 4; ++j) {
            float own = acc[ai][ni][j];
            float par = __shfl_xor(own, 1);
            int s = (rb + j) & (S_ - 1);
            float2 cs = reinterpret_cast<const float2*>(tab)[s * 64 + i2];
            Dst[(size_t)(rb + j) * 2048 + cc] = (bf16)((own * cs.x + sgn * par * cs.y) * scale);
          }
        }
      }
    }
  }
}

// ---------------- causal flash attention (unchanged from R4) ----------------
__global__ __launch_bounds__(512, 4)
void attn_fwd(const bf16* __restrict__ Q, const bf16* __restrict__ K,
              const bf16* __restrict__ Vt, bf16* __restrict__ O) {
  __shared__ bf16 Ks[2][64 * 128];
  __shared__ bf16 Vs[2][128 * 64];
  __shared__ bf16 Ps[8][16 * 64];
  const int tid = threadIdx.x;
  const int w = tid >> 6, l = tid & 63;
  const int lr = l & 15, lg = l >> 4;
  const int bx = blockIdx.x;
  const int h = blockIdx.y, b = blockIdx.z;
  const size_t bbase = (size_t)b * S_ * DM + (size_t)h * HD_;
  const bf16* vtb = Vt + (size_t)(b * H_ + h) * HD_ * S_;

#pragma unroll 1
  for (int pass = 0; pass < 2; ++pass) {
    const int qt = pass ? bx : (15 - bx);
    const int q0 = qt * 128 + w * 16;
    const int ktmax = 2 * qt + 1;

    bf16x8 qf[4];
#pragma unroll
    for (int kb = 0; kb < 4; ++kb)
      qf[kb] = *reinterpret_cast<const bf16x8*>(Q + bbase + (size_t)(q0 + lr) * DM + kb * 32 + lg * 8);

    float m_r = -INFINITY;
    float l_r = 0.f;
    f32x4 o[8] = {};

#pragma unroll
    for (int i = 0; i < 2; ++i) {
      int X = w * 2048 + i * 1024 + l * 16;
      int r = X >> 8, scb = (X & 255) ^ ((r & 7) << 4);
      gload_lds16(K + bbase + (size_t)r * DM + (scb >> 1), &Ks[0][(w * 2048 + i * 1024) >> 1]);
    }
#pragma unroll
    for (int i = 0; i < 2; ++i) {
      int X = w * 2048 + i * 1024 + l * 16;
      int d = X >> 7, scb = (X & 127) ^ ((d & 7) << 4);
      gload_lds16(vtb + (size_t)d * S_ + (scb >> 1), &Vs[0][(w * 2048 + i * 1024) >> 1]);
    }

    for (int kt = 0; kt <= ktmax; ++kt) {
      const int buf = kt & 1;
      if (kt < ktmax) {
        const int nk = (kt + 1) * 64;
#pragma unroll
        for (int i = 0; i < 2; ++i) {
          int X = w * 2048 + i * 1024 + l * 16;
          int r = X >> 8, scb = (X & 255) ^ ((r & 7) << 4);
          gload_lds16(K + bbase + (size_t)(nk + r) * DM + (scb >> 1),
                      &Ks[buf ^ 1][(w * 2048 + i * 1024) >> 1]);
        }
#pragma unroll
        for (int i = 0; i < 2; ++i) {
          int X = w * 2048 + i * 1024 + l * 16;
          int d = X >> 7, scb = (X & 127) ^ ((d & 7) << 4);
          gload_lds16(vtb + (size_t)d * S_ + nk + (scb >> 1),
                      &Vs[buf ^ 1][(w * 2048 + i * 1024) >> 1]);
        }
        asm volatile("s_waitcnt vmcnt(4)" ::: "memory");
      } else {
        asm volatile("s_waitcnt vmcnt(0)" ::: "memory");
      }
      __builtin_amdgcn_s_barrier();

      f32x4 sc4[4];
      __builtin_amdgcn_s_setprio(1);
#pragma unroll
      for (int cb = 0; cb < 4; ++cb) {
        sc4[cb] = f32x4{0.f, 0.f, 0.f, 0.f};
        int r = cb * 16 + lr;
#pragma unroll
        for (int kb = 0; kb < 4; ++kb) {
          int off = r * 256 + ((kb * 64 + lg * 16) ^ ((lr & 7) << 4));
          bf16x8 kf = *reinterpret_cast<const bf16x8*>((const char*)Ks[buf] + off);
          sc4[cb] = __builtin_amdgcn_mfma_f32_16x16x32_bf16(kf, qf[kb], sc4[cb], 0, 0, 0);
        }
      }
      __builtin_amdgcn_s_setprio(0);

      const int kv0 = kt * 64;
      if (kv0 + 63 > q0) {
        const int qq = q0 + lr;
#pragma unroll
        for (int cb = 0; cb < 4; ++cb)
#pragma unroll
          for (int jj = 0; jj < 4; ++jj)
            if (kv0 + cb * 16 + lg * 4 + jj > qq) sc4[cb][jj] = -INFINITY;
      }

      float tm = -INFINITY;
#pragma unroll
      for (int cb = 0; cb < 4; ++cb)
#pragma unroll
        for (int jj = 0; jj < 4; ++jj) tm = fmaxf(tm, sc4[cb][jj]);
      tm = fmaxf(tm, __shfl_xor(tm, 16));
      tm = fmaxf(tm, __shfl_xor(tm, 32));
      float mnew = fmaxf(m_r, tm);
      float sc_f = __expf(m_r - mnew);
      m_r = mnew;
      float rs = 0.f;
#pragma unroll
      for (int cb = 0; cb < 4; ++cb)
#pragma unroll
        for (int jj = 0; jj < 4; ++jj) {
          float p = __expf(sc4[cb][jj] - mnew);
          sc4[cb][jj] = p;
          rs += p;
        }
      rs += __shfl_xor(rs, 16);
      rs += __shfl_xor(rs, 32);
      l_r = l_r * sc_f + rs;

      float scO[4];
#pragma unroll
      for (int j = 0; j < 4; ++j) scO[j] = __shfl(sc_f, lg * 4 + j);
#pragma unroll
      for (int nb = 0; nb < 8; ++nb)
#pragma unroll
        for (int j = 0; j < 4; ++j) o[nb][j] *= scO[j];

#pragma unroll
      for (int cb = 0; cb < 4; ++cb) {
        bf16x4 pk = { (bf16)sc4[cb][0], (bf16)sc4[cb][1], (bf16)sc4[cb][2], (bf16)sc4[cb][3] };
        int off = lr * 128 + ((cb * 32 + lg * 8) ^ ((lr & 7) << 4));
        *reinterpret_cast<bf16x4*>((char*)Ps[w] + off) = pk;
      }

      bf16x8 pf[2];
#pragma unroll
      for (int kc = 0; kc < 2; ++kc) {
        int off = lr * 128 + ((kc * 64 + lg * 16) ^ ((lr & 7) << 4));
        pf[kc] = *reinterpret_cast<const bf16x8*>((const char*)Ps[w] + off);
      }
      __builtin_amdgcn_s_setprio(1);
#pragma unroll
      for (int nb = 0; nb < 8; ++nb) {
        int d = nb * 16 + lr;
#pragma unroll
        for (int kc = 0; kc < 2; ++kc) {
          int off = d * 128 + ((kc * 64 + lg * 16) ^ ((lr & 7) << 4));
          bf16x8 vf = *reinterpret_cast<const bf16x8*>((const char*)Vs[buf] + off);
          o[nb] = __builtin_amdgcn_mfma_f32_16x16x32_bf16(pf[kc], vf, o[nb], 0, 0, 0);
        }
      }
      __builtin_amdgcn_s_setprio(0);

      asm volatile("s_waitcnt lgkmcnt(0)" ::: "memory");
      __builtin_amdgcn_s_barrier();
    }

    float lO[4];
#pragma unroll
    for (int j = 0; j < 4; ++j) lO[j] = __shfl(l_r, lg * 4 + j);
#pragma unroll
    for (int j = 0; j < 4; ++j) {
      float inv = 1.0f / lO[j];
      size_t rowoff = bbase + (size_t)(q0 + lg * 4 + j) * DM;
#pragma unroll
      for (int nb = 0; nb < 8; ++nb)
        O[rowoff + nb * 16 + lr] = (bf16)(o[nb][j] * inv);
    }
  }
}

extern "C" void kernel_launch(void* const* d_in, const int* in_sizes, int n_in,
                              void* d_out, int out_size, void* d_ws, size_t ws_size,
                              hipStream_t stream) {
  const float* x  = (const float*)d_in[0];
  const float* Wq = (const float*)d_in[1];
  const float* Wk = (const float*)d_in[2];
  const float* Wv = (const float*)d_in[3];
  const float* Wo = (const float*)d_in[4];
  const float* bo = (const float*)d_in[5];
  float* out = (float*)d_out;

  const size_t NX = (size_t)B_ * S_ * DM;  // 16,777,216
  const size_t NW = (size_t)DM * DM;       //  4,194,304
  char* ws = (char*)d_ws;
  bf16* xb   = (bf16*)ws; ws += NX * 2;
  bf16* wqkv = (bf16*)ws; ws += 3 * NW * 2;  // [Wq;Wk;Wv] as one [6144][2048]
  bf16* wob  = (bf16*)ws; ws += NW * 2;
  bf16* qb   = (bf16*)ws; ws += NX * 2;
  bf16* kb   = (bf16*)ws; ws += NX * 2;
  bf16* vt   = (bf16*)ws; ws += NX * 2;   // V pre-transposed [B][H][HD][S]
  bf16* ctxb = (bf16*)ws; ws += NX * 2;
  float* tab = (float*)ws; ws += (size_t)S_ * 64 * 2 * sizeof(float);

  cast_f32_bf16<<<(int)((NX / 4 + 255) / 256), 256, 0, stream>>>(x, xb, (int)(NX / 4));
  cast_f32_bf16<<<(int)((NW / 4 + 255) / 256), 256, 0, stream>>>(Wq, wqkv, (int)(NW / 4));
  cast_f32_bf16<<<(int)((NW / 4 + 255) / 256), 256, 0, stream>>>(Wk, wqkv + NW, (int)(NW / 4));
  cast_f32_bf16<<<(int)((NW / 4 + 255) / 256), 256, 0, stream>>>(Wv, wqkv + 2 * NW, (int)(NW / 4));
  cast_f32_bf16<<<(int)((NW / 4 + 255) / 256), 256, 0, stream>>>(Wo, wob, (int)(NW / 4));
  rope_table_k<<<(S_ * 64 + 255) / 256, 256, 0, stream>>>(tab);

  const int M = B_ * S_;
  // fused QKV projection + RoPE + V-transpose: C[8192][6144]
  gemm8p<0><<<dim3(3 * DM / 256, M / 256), 512, 0, stream>>>(
      xb, wqkv, qb, kb, vt, nullptr, nullptr, tab, 3 * DM, DM);

  attn_fwd<<<dim3(8, H_, B_), 512, 0, stream>>>(qb, kb, vt, ctxb);

  // output projection + bias (f32 out)
  gemm8p<1><<<dim3(DM / 256, M / 256), 512, 0, stream>>>(
      ctxb, wob, nullptr, nullptr, nullptr, out, bo, nullptr, DM, DM);
}

// Round 8
// 418.430 us; speedup vs baseline: 2.3602x; 1.0486x over previous
//
#include <hip/hip_runtime.h>
#include <hip/hip_bf16.h>
#include <math.h>

#define B_  4
#define S_  2048
#define DM  2048
#define H_  16
#define HD_ 128

typedef __bf16 bf16;
typedef __bf16 bf16x4 __attribute__((ext_vector_type(4)));
typedef __bf16 bf16x8 __attribute__((ext_vector_type(8)));
typedef float  f32x4  __attribute__((ext_vector_type(4)));

__device__ __forceinline__ void gload_lds16(const bf16* g, bf16* l) {
  __builtin_amdgcn_global_load_lds(
      (const __attribute__((address_space(1))) void*)g,
      (__attribute__((address_space(3))) void*)l, 16, 0, 0);
}

// ---------------- fused cast fp32 -> bf16 for x + 4 weights ----------------
#define NX4 4194304   // (B*S*DM)/4
#define NW4 1048576   // (DM*DM)/4
__global__ void cast_all(const float* __restrict__ x, const float* __restrict__ wq,
                         const float* __restrict__ wk, const float* __restrict__ wv,
                         const float* __restrict__ wo,
                         bf16* __restrict__ xb, bf16* __restrict__ wqkv,
                         bf16* __restrict__ wob) {
  const int total = NX4 + 4 * NW4;
  int stride = gridDim.x * blockDim.x;
  for (int i = blockIdx.x * blockDim.x + threadIdx.x; i < total; i += stride) {
    const float* src; bf16* dst; int j;
    if (i < NX4) { src = x; dst = xb; j = i; }
    else {
      int t = i - NX4; int r = t >> 20; j = t & (NW4 - 1);
      if      (r == 0) { src = wq; dst = wqkv; }
      else if (r == 1) { src = wk; dst = wqkv + (size_t)NW4 * 4; }
      else if (r == 2) { src = wv; dst = wqkv + (size_t)NW4 * 8; }
      else             { src = wo; dst = wob; }
    }
    float4 v = reinterpret_cast<const float4*>(src)[j];
    bf16x4 o = { (bf16)v.x, (bf16)v.y, (bf16)v.z, (bf16)v.w };
    reinterpret_cast<bf16x4*>(dst)[j] = o;
  }
}

// ---------------- RoPE cos/sin table: tab[s][i] = {cos, sin} ----------------
__global__ void rope_table_k(float* __restrict__ tab) {
  int idx = blockIdx.x * blockDim.x + threadIdx.x;
  if (idx >= S_ * (HD_ / 2)) return;
  int pos = idx >> 6, i = idx & 63;
  float inv = powf(10000.0f, -(2.0f * i) / (float)HD_);
  float ang = (float)pos * inv;
  tab[2 * idx]     = cosf(ang);
  tab[2 * idx + 1] = sinf(ang);
}

// ---------------- phase-split bf16 GEMM: C[M,N] = A[M,K] * Bt[N,K]^T ----------------
// BM=BN=256, BK=64, 8 waves (2M x 4N). Two 64KB buffers, K-half-slot layout.
// 4 phases/K-tile, rolling 2-gload stage, gates vmcnt(8)+barrier at ph0/ph2.
// XCD swizzle: same-A-panel blocks co-located per XCD (requires gridDim.y%8==0).
// EPI=0: fused QKV epilogue (rope-Q / rope-K / transpose-V); EPI=1: f32 + bias.
template<int EPI>
__global__ __launch_bounds__(512, 2)
void gemm8p(const bf16* __restrict__ A, const bf16* __restrict__ Bt,
            bf16* __restrict__ Oq, bf16* __restrict__ Ok, bf16* __restrict__ Ovt,
            float* __restrict__ Cf, const float* __restrict__ bias,
            const float* __restrict__ tab, int N, int K) {
  __shared__ char lds[131072];
  const int tid = threadIdx.x;
  const int w = tid >> 6, l = tid & 63;
  const int lr = l & 15, lg = l >> 4;
  const int wm = w >> 2, wn = w & 3;
  // XCD-locality block remap
  const int L = blockIdx.x + gridDim.x * blockIdx.y;
  const int xcd = L & 7, s = L >> 3;
  const int rpx = gridDim.y >> 3;
  const int qq_ = s / gridDim.x;
  const int by = xcd * rpx + qq_;
  const int bx = s - qq_ * gridDim.x;
  const int row0 = by * 256, col0 = bx * 256;
  const int NT = K >> 6;

  auto stageSlot = [&](int isB, int kh, int kt2) {
    const bf16* src = isB ? (Bt + (size_t)col0 * K) : (A + (size_t)row0 * K);
    char* dstbase = (char*)lds + (kt2 & 1) * 65536 + isB * 32768 + kh * 16384;
    const int kcol = kt2 * 64 + kh * 32;
#pragma unroll
    for (int u = 0; u < 2; ++u) {
      int D = w * 2048 + u * 1024 + l * 16;
      int r = D >> 6, cb = D & 63;
      int sc = cb ^ (((r >> 1) & 3) << 4);
      gload_lds16(src + (size_t)r * K + kcol + (sc >> 1),
                  (bf16*)(dstbase + w * 2048 + u * 1024));
    }
  };

  const int swzt = ((lr >> 1) & 3) << 4;
  int offA[2][4], offB[4];
#pragma unroll
  for (int qm = 0; qm < 2; ++qm)
#pragma unroll
    for (int mi = 0; mi < 4; ++mi) {
      int r = wm * 128 + qm * 64 + mi * 16 + lr;
      offA[qm][mi] = r * 64 + ((lg * 16) ^ swzt);
    }
#pragma unroll
  for (int ni = 0; ni < 4; ++ni) {
    int r = wn * 64 + ni * 16 + lr;
    offB[ni] = 32768 + r * 64 + ((lg * 16) ^ swzt);
  }

  f32x4 acc[8][4] = {};

  stageSlot(0, 0, 0); stageSlot(1, 0, 0);
  stageSlot(0, 1, 0); stageSlot(1, 1, 0);
  if (NT > 1) { stageSlot(0, 0, 1); stageSlot(1, 0, 1); }

#pragma unroll 1
  for (int kt = 0; kt < NT; ++kt) {
    const char* bufb = (const char*)lds + (kt & 1) * 65536;
#pragma unroll
    for (int q = 0; q < 4; ++q) {
      const int kh = q >> 1;
      const int qmm = (q & 1);
      if (q == 0) {
        if (kt + 1 < NT) asm volatile("s_waitcnt vmcnt(8)" ::: "memory");
        else             asm volatile("s_waitcnt vmcnt(4)" ::: "memory");
        __builtin_amdgcn_s_barrier();
      } else if (q == 2) {
        if (kt + 1 < NT) asm volatile("s_waitcnt vmcnt(8)" ::: "memory");
        else             asm volatile("s_waitcnt vmcnt(0)" ::: "memory");
        __builtin_amdgcn_s_barrier();
      }
      const char* bb = bufb + kh * 16384;
      bf16x8 af[4], bfr[4];
#pragma unroll
      for (int mi = 0; mi < 4; ++mi)
        af[mi] = *reinterpret_cast<const bf16x8*>(bb + offA[qmm][mi]);
#pragma unroll
      for (int ni = 0; ni < 4; ++ni)
        bfr[ni] = *reinterpret_cast<const bf16x8*>(bb + offB[ni]);
      if (q < 2) { if (kt + 1 < NT) stageSlot(q & 1, 1, kt + 1); }
      else       { if (kt + 2 < NT) stageSlot(q & 1, 0, kt + 2); }
      __builtin_amdgcn_s_barrier();
      __builtin_amdgcn_s_setprio(1);
#pragma unroll
      for (int mi = 0; mi < 4; ++mi)
#pragma unroll
        for (int ni = 0; ni < 4; ++ni)
          acc[qmm * 4 + mi][ni] =
              __builtin_amdgcn_mfma_f32_16x16x32_bf16(af[mi], bfr[ni], acc[qmm * 4 + mi][ni], 0, 0, 0);
      __builtin_amdgcn_s_setprio(0);
    }
  }

  // ---- epilogue ----
#pragma unroll
  for (int ai = 0; ai < 8; ++ai) {
    int rb = row0 + wm * 128 + ai * 16 + lg * 4;
#pragma unroll
    for (int ni = 0; ni < 4; ++ni) {
      int gc = col0 + wn * 64 + ni * 16 + lr;
      if (EPI == 1) {
#pragma unroll
        for (int j = 0; j < 4; ++j)
          Cf[(size_t)(rb + j) * N + gc] = acc[ai][ni][j] + bias[gc];
      } else {
        int reg = col0 >> 11;     // uniform per block: 0=Q, 1=K, 2=V
        int cc = gc & 2047;
        if (reg == 2) {
          int bb2 = rb >> 11, ss = rb & 2047;
          int hh = cc >> 7, dd = cc & 127;
          bf16x4 pack = { (bf16)acc[ai][ni][0], (bf16)acc[ai][ni][1],
                          (bf16)acc[ai][ni][2], (bf16)acc[ai][ni][3] };
          *reinterpret_cast<bf16x4*>(Ovt + (((size_t)(bb2 * H_ + hh) * HD_ + dd) << 11) + ss) = pack;
        } else {
          bf16* Dst = (reg == 0) ? Oq : Ok;
          float scale = (reg == 0) ? 0.08838834764831845f : 1.0f;
          int i2 = (cc & 127) >> 1;
          float sgn = (lr & 1) ? 1.0f : -1.0f;
#pragma unroll
          for (int j = 0; j < 4; ++j) {
            float own = acc[ai][ni][j];
            float par = __shfl_xor(own, 1);
            int ss = (rb + j) & (S_ - 1);
            float2 cs = reinterpret_cast<const float2*>(tab)[ss * 64 + i2];
            Dst[(size_t)(rb + j) * 2048 + cc] = (bf16)((own * cs.x + sgn * par * cs.y) * scale);
          }
        }
      }
    }
  }
}

// ---------------- causal flash attention ----------------
// 8 waves, paired q-tiles (uniform 36 KV-tiles/block), swapped QK^T,
// XOR-swizzled K/Vt LDS, double-buffered counted vmcnt(4), T13 defer-max.
// XCD swizzle: all 8 q-blocks of one (b,h) co-located per XCD.
__global__ __launch_bounds__(512, 4)
void attn_fwd(const bf16* __restrict__ Q, const bf16* __restrict__ K,
              const bf16* __restrict__ Vt, bf16* __restrict__ O) {
  __shared__ bf16 Ks[2][64 * 128];
  __shared__ bf16 Vs[2][128 * 64];
  __shared__ bf16 Ps[8][16 * 64];
  const int tid = threadIdx.x;
  const int w = tid >> 6, l = tid & 63;
  const int lr = l & 15, lg = l >> 4;
  // XCD-locality remap: p = (b,h) pair, all its bx on one XCD
  const int L = blockIdx.x + 8 * (blockIdx.y + 16 * blockIdx.z);
  const int xcd = L & 7, s = L >> 3;
  const int p = xcd * 8 + (s & 7);
  const int bx = s >> 3;
  const int h = p & 15, b = p >> 4;
  const size_t bbase = (size_t)b * S_ * DM + (size_t)h * HD_;
  const bf16* vtb = Vt + (size_t)(b * H_ + h) * HD_ * S_;

#pragma unroll 1
  for (int pass = 0; pass < 2; ++pass) {
    const int qt = pass ? bx : (15 - bx);
    const int q0 = qt * 128 + w * 16;
    const int ktmax = 2 * qt + 1;

    bf16x8 qf[4];
#pragma unroll
    for (int kb = 0; kb < 4; ++kb)
      qf[kb] = *reinterpret_cast<const bf16x8*>(Q + bbase + (size_t)(q0 + lr) * DM + kb * 32 + lg * 8);

    float m_r = -INFINITY;
    float l_r = 0.f;
    f32x4 o[8] = {};

#pragma unroll
    for (int i = 0; i < 2; ++i) {
      int X = w * 2048 + i * 1024 + l * 16;
      int r = X >> 8, scb = (X & 255) ^ ((r & 7) << 4);
      gload_lds16(K + bbase + (size_t)r * DM + (scb >> 1), &Ks[0][(w * 2048 + i * 1024) >> 1]);
    }
#pragma unroll
    for (int i = 0; i < 2; ++i) {
      int X = w * 2048 + i * 1024 + l * 16;
      int d = X >> 7, scb = (X & 127) ^ ((d & 7) << 4);
      gload_lds16(vtb + (size_t)d * S_ + (scb >> 1), &Vs[0][(w * 2048 + i * 1024) >> 1]);
    }

    for (int kt = 0; kt <= ktmax; ++kt) {
      const int buf = kt & 1;
      if (kt < ktmax) {
        const int nk = (kt + 1) * 64;
#pragma unroll
        for (int i = 0; i < 2; ++i) {
          int X = w * 2048 + i * 1024 + l * 16;
          int r = X >> 8, scb = (X & 255) ^ ((r & 7) << 4);
          gload_lds16(K + bbase + (size_t)(nk + r) * DM + (scb >> 1),
                      &Ks[buf ^ 1][(w * 2048 + i * 1024) >> 1]);
        }
#pragma unroll
        for (int i = 0; i < 2; ++i) {
          int X = w * 2048 + i * 1024 + l * 16;
          int d = X >> 7, scb = (X & 127) ^ ((d & 7) << 4);
          gload_lds16(vtb + (size_t)d * S_ + nk + (scb >> 1),
                      &Vs[buf ^ 1][(w * 2048 + i * 1024) >> 1]);
        }
        asm volatile("s_waitcnt vmcnt(4)" ::: "memory");
      } else {
        asm volatile("s_waitcnt vmcnt(0)" ::: "memory");
      }
      __builtin_amdgcn_s_barrier();

      f32x4 sc4[4];
      __builtin_amdgcn_s_setprio(1);
#pragma unroll
      for (int cb = 0; cb < 4; ++cb) {
        sc4[cb] = f32x4{0.f, 0.f, 0.f, 0.f};
        int r = cb * 16 + lr;
#pragma unroll
        for (int kb = 0; kb < 4; ++kb) {
          int off = r * 256 + ((kb * 64 + lg * 16) ^ ((lr & 7) << 4));
          bf16x8 kf = *reinterpret_cast<const bf16x8*>((const char*)Ks[buf] + off);
          sc4[cb] = __builtin_amdgcn_mfma_f32_16x16x32_bf16(kf, qf[kb], sc4[cb], 0, 0, 0);
        }
      }
      __builtin_amdgcn_s_setprio(0);

      const int kv0 = kt * 64;
      if (kv0 + 63 > q0) {
        const int qq = q0 + lr;
#pragma unroll
        for (int cb = 0; cb < 4; ++cb)
#pragma unroll
          for (int jj = 0; jj < 4; ++jj)
            if (kv0 + cb * 16 + lg * 4 + jj > qq) sc4[cb][jj] = -INFINITY;
      }

      // ---- online softmax with T13 defer-max ----
      float tm = -INFINITY;
#pragma unroll
      for (int cb = 0; cb < 4; ++cb)
#pragma unroll
        for (int jj = 0; jj < 4; ++jj) tm = fmaxf(tm, sc4[cb][jj]);
      tm = fmaxf(tm, __shfl_xor(tm, 16));
      tm = fmaxf(tm, __shfl_xor(tm, 32));
      const bool resc = !__all(tm <= m_r + 8.0f);   // wave-uniform
      float sc_f = 1.f;
      if (resc) {
        float mnew = fmaxf(m_r, tm);
        sc_f = __expf(m_r - mnew);
        m_r = mnew;
      }
      float rs = 0.f;
#pragma unroll
      for (int cb = 0; cb < 4; ++cb)
#pragma unroll
        for (int jj = 0; jj < 4; ++jj) {
          float pp = __expf(sc4[cb][jj] - m_r);
          sc4[cb][jj] = pp;
          rs += pp;
        }
      rs += __shfl_xor(rs, 16);
      rs += __shfl_xor(rs, 32);
      l_r = l_r * sc_f + rs;
      if (resc) {
        float scO[4];
#pragma unroll
        for (int j = 0; j < 4; ++j) scO[j] = __shfl(sc_f, lg * 4 + j);
#pragma unroll
        for (int nb = 0; nb < 8; ++nb)
#pragma unroll
          for (int j = 0; j < 4; ++j) o[nb][j] *= scO[j];
      }

#pragma unroll
      for (int cb = 0; cb < 4; ++cb) {
        bf16x4 pk = { (bf16)sc4[cb][0], (bf16)sc4[cb][1], (bf16)sc4[cb][2], (bf16)sc4[cb][3] };
        int off = lr * 128 + ((cb * 32 + lg * 8) ^ ((lr & 7) << 4));
        *reinterpret_cast<bf16x4*>((char*)Ps[w] + off) = pk;
      }

      bf16x8 pf[2];
#pragma unroll
      for (int kc = 0; kc < 2; ++kc) {
        int off = lr * 128 + ((kc * 64 + lg * 16) ^ ((lr & 7) << 4));
        pf[kc] = *reinterpret_cast<const bf16x8*>((const char*)Ps[w] + off);
      }
      __builtin_amdgcn_s_setprio(1);
#pragma unroll
      for (int nb = 0; nb < 8; ++nb) {
        int d = nb * 16 + lr;
#pragma unroll
        for (int kc = 0; kc < 2; ++kc) {
          int off = d * 128 + ((kc * 64 + lg * 16) ^ ((lr & 7) << 4));
          bf16x8 vf = *reinterpret_cast<const bf16x8*>((const char*)Vs[buf] + off);
          o[nb] = __builtin_amdgcn_mfma_f32_16x16x32_bf16(pf[kc], vf, o[nb], 0, 0, 0);
        }
      }
      __builtin_amdgcn_s_setprio(0);

      asm volatile("s_waitcnt lgkmcnt(0)" ::: "memory");
      __builtin_amdgcn_s_barrier();
    }

    float lO[4];
#pragma unroll
    for (int j = 0; j < 4; ++j) lO[j] = __shfl(l_r, lg * 4 + j);
#pragma unroll
    for (int j = 0; j < 4; ++j) {
      float inv = 1.0f / lO[j];
      size_t rowoff = bbase + (size_t)(q0 + lg * 4 + j) * DM;
#pragma unroll
      for (int nb = 0; nb < 8; ++nb)
        O[rowoff + nb * 16 + lr] = (bf16)(o[nb][j] * inv);
    }
  }
}

extern "C" void kernel_launch(void* const* d_in, const int* in_sizes, int n_in,
                              void* d_out, int out_size, void* d_ws, size_t ws_size,
                              hipStream_t stream) {
  const float* x  = (const float*)d_in[0];
  const float* Wq = (const float*)d_in[1];
  const float* Wk = (const float*)d_in[2];
  const float* Wv = (const float*)d_in[3];
  const float* Wo = (const float*)d_in[4];
  const float* bo = (const float*)d_in[5];
  float* out = (float*)d_out;

  const size_t NX = (size_t)B_ * S_ * DM;  // 16,777,216
  const size_t NW = (size_t)DM * DM;       //  4,194,304
  char* ws = (char*)d_ws;
  bf16* xb   = (bf16*)ws; ws += NX * 2;
  bf16* wqkv = (bf16*)ws; ws += 3 * NW * 2;  // [Wq;Wk;Wv] as one [6144][2048]
  bf16* wob  = (bf16*)ws; ws += NW * 2;
  bf16* qb   = (bf16*)ws; ws += NX * 2;
  bf16* kb   = (bf16*)ws; ws += NX * 2;
  bf16* vt   = (bf16*)ws; ws += NX * 2;   // V pre-transposed [B][H][HD][S]
  bf16* ctxb = (bf16*)ws; ws += NX * 2;
  float* tab = (float*)ws; ws += (size_t)S_ * 64 * 2 * sizeof(float);

  cast_all<<<2048, 256, 0, stream>>>(x, Wq, Wk, Wv, Wo, xb, wqkv, wob);
  rope_table_k<<<(S_ * 64 + 255) / 256, 256, 0, stream>>>(tab);

  const int M = B_ * S_;
  // fused QKV projection + RoPE + V-transpose: C[8192][6144]
  gemm8p<0><<<dim3(3 * DM / 256, M / 256), 512, 0, stream>>>(
      xb, wqkv, qb, kb, vt, nullptr, nullptr, tab, 3 * DM, DM);

  attn_fwd<<<dim3(8, H_, B_), 512, 0, stream>>>(qb, kb, vt, ctxb);

  // output projection + bias (f32 out)
  gemm8p<1><<<dim3(DM / 256, M / 256), 512, 0, stream>>>(
      ctxb, wob, nullptr, nullptr, nullptr, out, bo, nullptr, DM, DM);
}